// Round 8
// baseline (10541.039 us; speedup 1.0000x reference)
//
#include <hip/hip_runtime.h>

#define TT   1024
#define BB   64
#define DIN  256
#define HH   512
#define DOUT 256

#define NWG_L0  64
#define NWG_L1  128
#define NWG_OUT 8
#define NWG_TOT 200
#define NBARRIERS (1 + (TT + 2))

typedef short bf16x8 __attribute__((ext_vector_type(8)));
typedef float f32x4  __attribute__((ext_vector_type(4)));

// frag-ordered bf16 tensors: index f = ((ks*4 + ct)*64 + lane), element e
// value = M[k = ks*32 + (lane>>4)*8 + e][col = ct*16 + (lane&15)]
__device__ bf16x8 g_xf[TT * 2048];     // x packed: 8 ks x 4 ct x 64 lanes per t (32 MB)
__device__ bf16x8 g_h1f[2][4096];      // h1 ring: 16 ks x 4 ct x 64
__device__ bf16x8 g_h2f[2][4096];      // h2 ring

// replay-safe epoch barrier state (zero-initialized at module load) — R6-proven design
__device__ unsigned g_arrive[NWG_TOT * 16];   // one u32 per 64B line
__device__ unsigned g_release;
__device__ unsigned g_epoch_base;

__device__ __forceinline__ void gridbar(unsigned e, int wg, int tid) {
    __syncthreads();
    if (tid == 0)
        __hip_atomic_store(&g_arrive[wg * 16], e, __ATOMIC_RELEASE, __HIP_MEMORY_SCOPE_AGENT);
    if (wg == 0) {
        for (int s = tid; s < NWG_TOT; s += 256) {
            while (__hip_atomic_load(&g_arrive[s * 16], __ATOMIC_RELAXED,
                                     __HIP_MEMORY_SCOPE_AGENT) != e) {}
        }
        __builtin_amdgcn_fence(__ATOMIC_ACQUIRE, "agent");
        __syncthreads();
        if (tid == 0)
            __hip_atomic_store(&g_release, e, __ATOMIC_RELEASE, __HIP_MEMORY_SCOPE_AGENT);
    } else {
        if (tid == 0) {
            while (__hip_atomic_load(&g_release, __ATOMIC_RELAXED,
                                     __HIP_MEMORY_SCOPE_AGENT) != e) {}
            __builtin_amdgcn_fence(__ATOMIC_ACQUIRE, "agent");
        }
        __syncthreads();
    }
}

__device__ __forceinline__ float sigf(float v) { return 1.f / (1.f + __expf(-v)); }
__device__ __forceinline__ float tanh_fast(float v) { return 2.f / (1.f + __expf(-2.f * v)) - 1.f; }

__device__ __forceinline__ short f2bf(float f) {   // RNE float->bf16 bits
    unsigned u = __builtin_bit_cast(unsigned, f);
    unsigned r = (u + 0x7FFFu + ((u >> 16) & 1u)) >> 16;
    return (short)r;
}

__device__ __forceinline__ bf16x8 pack8(float4 v0, float4 v1) {
    bf16x8 r;
    r[0] = f2bf(v0.x); r[1] = f2bf(v0.y); r[2] = f2bf(v0.z); r[3] = f2bf(v0.w);
    r[4] = f2bf(v1.x); r[5] = f2bf(v1.y); r[6] = f2bf(v1.z); r[7] = f2bf(v1.w);
    return r;
}

// ---------------- pre-pass: pack x (fp32 [T][B][DIN]) into frag-ordered bf16
extern "C" __global__ void __launch_bounds__(256)
pack_x(const float* __restrict__ x) {
    const int t = blockIdx.x, tid = threadIdx.x;
    const float* xt = x + (size_t)t * BB * DIN;
    bf16x8* dst = g_xf + (size_t)t * 2048;
    #pragma unroll
    for (int u = 0; u < 8; ++u) {
        const int f = u * 256 + tid;
        const int lane_ = f & 63, ctks = f >> 6;
        const int ct = ctks & 3, ks = ctks >> 2;
        const int b  = ct * 16 + (lane_ & 15);
        const int kb = ks * 32 + (lane_ >> 4) * 8;
        const float4* s = (const float4*)(xt + b * DIN + kb);
        dst[f] = pack8(s[0], s[1]);
    }
}

// ---------------- LSTM layer: WG = (unit-block ub, NCT batch-quadrants); wave = 4 units
// Staged B-frags are unit-independent -> all 4 waves share one LDS tile.
// L=0: K=768, NCT=2 (64 WGs); L=1: K=1024, NCT=1 (128 WGs)
template<int L, int NCT>
__device__ void run_layer(int lwg, int wg, int tid,
                          const float* __restrict__ wih, const float* __restrict__ whh,
                          const float* __restrict__ bih, const float* __restrict__ bhh,
                          float* __restrict__ out, unsigned ep, bf16x8* sB)
{
    constexpr int KINX = (L == 0) ? DIN : HH;
    constexpr int NKSA = KINX / 32;          // frag-rows from first operand (8 or 16)
    constexpr int NKS  = NKSA + HH / 32;     // total frag-rows (24 or 32)
    constexpr int ROWS = NKS * NCT;          // staged rows (48 or 32)
    constexpr int NST  = ROWS / 4;           // rows staged per wave (12 or 8)

    const int lane = tid & 63, lo = lane & 15, hi = lane >> 4;
    const int w      = tid >> 6;
    const int ctbase = (NCT == 2) ? (lwg & 1) * 2 : (lwg & 3);
    const int ub     = (NCT == 2) ? (lwg >> 1) : (lwg >> 2);
    const int wv     = ub * 4 + w;           // unit-group [0,128)
    const int jbase  = wv * 4;
    const int grow   = (lo & 3) * HH + jbase + (lo >> 2);  // gate-major A-row for lane lo

    // --- this wave's weights as bf16 A-fragments in registers (loaded once)
    bf16x8 aF[NKS];
    #pragma unroll
    for (int ks = 0; ks < NKS; ++ks) {
        const float* wr;
        if (ks < NKSA) wr = wih + (size_t)grow * KINX + ks * 32 + hi * 8;
        else           wr = whh + (size_t)grow * HH + (ks - NKSA) * 32 + hi * 8;
        const float4* p = (const float4*)wr;
        aF[ks] = pack8(p[0], p[1]);
    }

    f32x4 biasv;
    #pragma unroll
    for (int r = 0; r < 4; ++r)
        biasv[r] = bih[r * HH + jbase + hi] + bhh[r * HH + jbase + hi];

    // h-ring write slot for unit j = jbase+hi (frag coords) — validated R5/R6
    const int wksp = wv >> 3, wkhi = (wv >> 1) & 3, wel = (wv & 1) * 4 + hi;

    float cst[NCT];
    #pragma unroll
    for (int c = 0; c < NCT; ++c) cst[c] = 0.f;

    for (int s = 0; s <= TT + 1; ++s) {
        const int t = (L == 0) ? s : s - 1;
        if (t >= 0 && t < TT) {
            const bf16x8* srcA = (L == 0) ? (g_xf + (size_t)t * 2048) : g_h1f[t & 1];
            const bf16x8* srcB = (L == 0) ? g_h1f[(t + 1) & 1] : g_h2f[(t + 1) & 1];

            // ---- WG-cooperative stage: wave w loads rows ri = r*4+w, then ds_writes
            bf16x8 stg[NST];
            #pragma unroll
            for (int r = 0; r < NST; ++r) {
                const int ri = r * 4 + w;
                const int ks = ri / NCT, c = ri % NCT;
                const bf16x8* src = (ks < NKSA)
                    ? &srcA[(ks * 4 + ctbase + c) * 64 + lane]
                    : &srcB[((ks - NKSA) * 4 + ctbase + c) * 64 + lane];
                stg[r] = *src;
            }
            #pragma unroll
            for (int r = 0; r < NST; ++r)
                sB[(r * 4 + w) * 64 + lane] = stg[r];
            __syncthreads();

            f32x4 acc[NCT];
            #pragma unroll
            for (int c = 0; c < NCT; ++c) acc[c] = biasv;
            #pragma unroll
            for (int ks = 0; ks < NKS; ++ks)
                #pragma unroll
                for (int c = 0; c < NCT; ++c)
                    acc[c] = __builtin_amdgcn_mfma_f32_16x16x32_bf16(
                        aF[ks], sB[(ks * NCT + c) * 64 + lane], acc[c], 0, 0, 0);

            // lane (hi,lo): gates i,f,g,o for unit j=jbase+hi, batch b=ct*16+lo
            short* ringW = (short*)((L == 0) ? g_h1f[t & 1] : g_h2f[t & 1]);
            #pragma unroll
            for (int c = 0; c < NCT; ++c) {
                const int ct = ctbase + c;
                const float gi = acc[c][0], gf = acc[c][1];
                const float gg = acc[c][2], go = acc[c][3];
                const float cn_ = sigf(gf) * cst[c] + sigf(gi) * tanh_fast(gg);
                const float hv  = sigf(go) * tanh_fast(cn_);
                cst[c] = cn_;
                ringW[(((wksp * 4 + ct) * 64) + wkhi * 16 + lo) * 8 + wel] = f2bf(hv);
                if (t == TT - 1) {
                    const int j = jbase + hi, b = ct * 16 + lo;
                    const size_t base = (size_t)TT * BB * DOUT;
                    out[base + (size_t)L * BB * HH + (size_t)b * HH + j] = hv;
                    out[base + (size_t)2 * BB * HH + (size_t)L * BB * HH + (size_t)b * HH + j] = cn_;
                }
            }
        }
        gridbar(++ep, wg, tid);   // entry __syncthreads also fences sB reuse
    }
}

// ---------------- output projection: 8 WGs = (odim-block ob, ctpair); wave = 16 odims
__device__ void run_out(int lwg, int wg, int tid,
                        const float* __restrict__ wout, const float* __restrict__ bout,
                        float* __restrict__ out, unsigned ep, bf16x8* sB)
{
    constexpr int NKS  = HH / 32;   // 16 frag-rows
    constexpr int ROWS = NKS * 2;   // 32 staged rows
    constexpr int NST  = ROWS / 4;  // 8 per wave
    const int lane = tid & 63, lo = lane & 15, hi = lane >> 4;
    const int w = tid >> 6;
    const int ctbase = (lwg & 1) * 2, ob = lwg >> 1;
    const int obase = (ob * 4 + w) * 16;

    bf16x8 aF[NKS];
    #pragma unroll
    for (int ks = 0; ks < NKS; ++ks) {
        const float4* p = (const float4*)(wout + (size_t)(obase + lo) * HH + ks * 32 + hi * 8);
        aF[ks] = pack8(p[0], p[1]);
    }
    f32x4 biasv;
    #pragma unroll
    for (int r = 0; r < 4; ++r) biasv[r] = bout[obase + hi * 4 + r];

    for (int s = 0; s <= TT + 1; ++s) {
        const int t = s - 2;
        if (t >= 0 && t < TT) {
            const bf16x8* src = g_h2f[t & 1];
            bf16x8 stg[NST];
            #pragma unroll
            for (int r = 0; r < NST; ++r) {
                const int ri = r * 4 + w;
                const int ks = ri >> 1, c = ri & 1;
                stg[r] = src[(ks * 4 + ctbase + c) * 64 + lane];
            }
            #pragma unroll
            for (int r = 0; r < NST; ++r)
                sB[(r * 4 + w) * 64 + lane] = stg[r];
            __syncthreads();

            f32x4 acc[2] = {biasv, biasv};
            #pragma unroll
            for (int ks = 0; ks < NKS; ++ks)
                #pragma unroll
                for (int c = 0; c < 2; ++c)
                    acc[c] = __builtin_amdgcn_mfma_f32_16x16x32_bf16(
                        aF[ks], sB[(ks * 2 + c) * 64 + lane], acc[c], 0, 0, 0);
            #pragma unroll
            for (int c = 0; c < 2; ++c)
                #pragma unroll
                for (int r = 0; r < 4; ++r) {
                    const int b = (ctbase + c) * 16 + lo, o = obase + hi * 4 + r;
                    out[(size_t)t * BB * DOUT + (size_t)b * DOUT + o] = acc[c][r];
                }
        }
        gridbar(++ep, wg, tid);
    }
}

extern "C" __global__ void __launch_bounds__(256, 1)
lstm2_fused(const float* __restrict__ x,
            const float* __restrict__ wih0, const float* __restrict__ whh0,
            const float* __restrict__ bih0, const float* __restrict__ bhh0,
            const float* __restrict__ wih1, const float* __restrict__ whh1,
            const float* __restrict__ bih1, const float* __restrict__ bhh1,
            const float* __restrict__ wout, const float* __restrict__ bout,
            float* __restrict__ out)
{
    __shared__ bf16x8 sB[3072];   // 48KB: L0 uses all, L1/OUT use 32KB

    const int tid = threadIdx.x, wg = blockIdx.x;

    const unsigned base = __hip_atomic_load(&g_epoch_base, __ATOMIC_RELAXED,
                                            __HIP_MEMORY_SCOPE_AGENT);
    unsigned ep = base;

    // zero t=-1 parity ring buffers (h1f[1], h2f[1]) as uint4 lines
    {
        const int gidx = wg * 256 + tid;
        if (gidx < 4096) {
            ((uint4*)g_h1f[1])[gidx] = uint4{0, 0, 0, 0};
            ((uint4*)g_h2f[1])[gidx] = uint4{0, 0, 0, 0};
        }
    }
    gridbar(++ep, wg, tid);

    if (wg < NWG_L0)
        run_layer<0, 2>(wg, wg, tid, wih0, whh0, bih0, bhh0, out, ep, sB);
    else if (wg < NWG_L0 + NWG_L1)
        run_layer<1, 1>(wg - NWG_L0, wg, tid, wih1, whh1, bih1, bhh1, out, ep, sB);
    else
        run_out(wg - NWG_L0 - NWG_L1, wg, tid, wout, bout, out, ep, sB);

    if (wg == 0 && tid == 0)
        __hip_atomic_store(&g_epoch_base, base + NBARRIERS, __ATOMIC_RELAXED,
                           __HIP_MEMORY_SCOPE_AGENT);
}

extern "C" void kernel_launch(void* const* d_in, const int* in_sizes, int n_in,
                              void* d_out, int out_size, void* d_ws, size_t ws_size,
                              hipStream_t stream) {
    const float* x    = (const float*)d_in[0];
    const float* wih0 = (const float*)d_in[1];
    const float* whh0 = (const float*)d_in[2];
    const float* bih0 = (const float*)d_in[3];
    const float* bhh0 = (const float*)d_in[4];
    const float* wih1 = (const float*)d_in[5];
    const float* whh1 = (const float*)d_in[6];
    const float* bih1 = (const float*)d_in[7];
    const float* bhh1 = (const float*)d_in[8];
    const float* wout = (const float*)d_in[9];
    const float* bout = (const float*)d_in[10];
    float* out = (float*)d_out;

    hipLaunchKernelGGL(pack_x, dim3(TT), dim3(256), 0, stream, x);
    hipLaunchKernelGGL(lstm2_fused, dim3(NWG_TOT), dim3(256), 0, stream,
                       x, wih0, whh0, bih0, bhh0, wih1, whh1, bih1, bhh1,
                       wout, bout, out);
}

// Round 10
// 6784.882 us; speedup vs baseline: 1.5536x; 1.5536x over previous
//
#include <hip/hip_runtime.h>

#define TT   1024
#define BB   64
#define DIN  256
#define HH   512
#define DOUT 256

#define NWG_L0  64
#define NWG_L1  128
#define NWG_OUT 8
#define NWG_TOT 200
#define NBARRIERS (1 + (TT + 2))

typedef short bf16x8 __attribute__((ext_vector_type(8)));
typedef float f32x4  __attribute__((ext_vector_type(4)));
typedef unsigned u32x4 __attribute__((ext_vector_type(4)));

// frag-ordered bf16 tensors: index f = ((ks*4 + ct)*64 + lane), element e
// value = M[k = ks*32 + (lane>>4)*8 + e][col = ct*16 + (lane&15)]
__device__ bf16x8 g_xf[TT * 2048];     // x packed (static, cached path)
__device__ bf16x8 g_h1f[2][4096];      // h1 ring (coherent-bypass path)
__device__ bf16x8 g_h2f[2][4096];      // h2 ring (coherent-bypass path)

__device__ unsigned g_flags[256];      // one-hop barrier flags (padded to 256)
__device__ unsigned g_epoch_base;

// ---------- explicitly-coherent (IF-level) memory primitives: bypass L1+L2
__device__ __forceinline__ u32x4 ldg_cv16(const void* p) {
    u32x4 r;
    asm volatile("global_load_dwordx4 %0, %1, off sc0 sc1"
                 : "=&v"(r) : "v"(p) : "memory");
    return r;
}
__device__ __forceinline__ void stg_cv16(void* p, u32x4 v) {
    asm volatile("global_store_dwordx4 %0, %1, off sc0 sc1" :: "v"(p), "v"(v) : "memory");
}
__device__ __forceinline__ void stg_cv_u32(void* p, unsigned v) {
    asm volatile("global_store_dword %0, %1, off sc0 sc1" :: "v"(p), "v"(v) : "memory");
}
__device__ __forceinline__ void stg_cv_u16(void* p, unsigned v) {
    asm volatile("global_store_short %0, %1, off sc0 sc1" :: "v"(p), "v"(v) : "memory");
}
__device__ __forceinline__ void wait_vm0(void) {
    asm volatile("s_waitcnt vmcnt(0)" ::: "memory");
}

// ---------- one-hop grid barrier: every WG self-detects on 256 padded flags
__device__ __forceinline__ void gridbar(unsigned e, int wg, int tid) {
    wait_vm0();                 // all this WG's bypass stores have reached IF
    __syncthreads();            // every wave of the WG drained
    if (tid == 0) stg_cv_u32(&g_flags[wg], e);
    if (tid < 64) {
        const unsigned* p0 = &g_flags[tid];
        const unsigned* p1 = &g_flags[tid + 64];
        const unsigned* p2 = &g_flags[tid + 128];
        const unsigned* p3 = &g_flags[tid + 192];
        for (;;) {
            unsigned v0, v1, v2, v3;
            asm volatile("global_load_dword %0, %4, off sc0 sc1\n\t"
                         "global_load_dword %1, %5, off sc0 sc1\n\t"
                         "global_load_dword %2, %6, off sc0 sc1\n\t"
                         "global_load_dword %3, %7, off sc0 sc1\n\t"
                         "s_waitcnt vmcnt(0)"
                         : "=&v"(v0), "=&v"(v1), "=&v"(v2), "=&v"(v3)
                         : "v"(p0), "v"(p1), "v"(p2), "v"(p3)
                         : "memory");
            const int ok = (v0 >= e) & (v1 >= e) & (v2 >= e) & (v3 >= e);
            if (__all(ok)) break;
            __builtin_amdgcn_s_sleep(1);
        }
    }
    __syncthreads();
}

__device__ __forceinline__ float sigf(float v) { return 1.f / (1.f + __expf(-v)); }
__device__ __forceinline__ float tanh_fast(float v) { return 2.f / (1.f + __expf(-2.f * v)) - 1.f; }

__device__ __forceinline__ short f2bf(float f) {   // RNE float->bf16 bits
    unsigned u = __builtin_bit_cast(unsigned, f);
    unsigned r = (u + 0x7FFFu + ((u >> 16) & 1u)) >> 16;
    return (short)r;
}

__device__ __forceinline__ bf16x8 pack8(float4 v0, float4 v1) {
    bf16x8 r;
    r[0] = f2bf(v0.x); r[1] = f2bf(v0.y); r[2] = f2bf(v0.z); r[3] = f2bf(v0.w);
    r[4] = f2bf(v1.x); r[5] = f2bf(v1.y); r[6] = f2bf(v1.z); r[7] = f2bf(v1.w);
    return r;
}

// ---------------- pre-pass: pack x (fp32 [T][B][DIN]) into frag-ordered bf16
extern "C" __global__ void __launch_bounds__(256)
pack_x(const float* __restrict__ x) {
    const int t = blockIdx.x, tid = threadIdx.x;
    const float* xt = x + (size_t)t * BB * DIN;
    bf16x8* dst = g_xf + (size_t)t * 2048;
    #pragma unroll
    for (int u = 0; u < 8; ++u) {
        const int f = u * 256 + tid;
        const int lane_ = f & 63, ctks = f >> 6;
        const int ct = ctks & 3, ks = ctks >> 2;
        const int b  = ct * 16 + (lane_ & 15);
        const int kb = ks * 32 + (lane_ >> 4) * 8;
        const float4* s = (const float4*)(xt + b * DIN + kb);
        dst[f] = pack8(s[0], s[1]);
    }
}

// ---------------- LSTM layer: WG = (unit-block, NCT batch-quadrants); wave = 4 units
// L=0: K=768, NCT=2 (64 WGs, x-rows cached, h-rows bypass)
// L=1: K=1024, NCT=1 (128 WGs, all rows bypass)
template<int L, int NCT>
__device__ void run_layer(int lwg, int wg, int tid,
                          const float* __restrict__ wih, const float* __restrict__ whh,
                          const float* __restrict__ bih, const float* __restrict__ bhh,
                          float* __restrict__ out, unsigned ep, bf16x8* sB)
{
    constexpr int KINX = (L == 0) ? DIN : HH;
    constexpr int NKSA = KINX / 32;          // frag-rows from first operand (8 or 16)
    constexpr int NKS  = NKSA + HH / 32;     // total frag-rows (24 or 32)
    constexpr int ROWS = NKS * NCT;          // staged rows (48 or 32)
    constexpr int NST  = ROWS / 4;           // rows staged per wave (12 or 8)
    constexpr int NCXR = (L == 0) ? (NKSA * NCT / 4) : 0;  // cached rounds (x-rows)

    const int lane = tid & 63, lo = lane & 15, hi = lane >> 4;
    const int w      = tid >> 6;
    const int ctbase = (NCT == 2) ? (lwg & 1) * 2 : (lwg & 3);
    const int ub     = (NCT == 2) ? (lwg >> 1) : (lwg >> 2);
    const int wv     = ub * 4 + w;           // unit-group [0,128)
    const int jbase  = wv * 4;
    const int grow   = (lo & 3) * HH + jbase + (lo >> 2);  // gate-major A-row for lane lo

    // --- this wave's weights as bf16 A-fragments in registers (loaded once, cached)
    bf16x8 aF[NKS];
    #pragma unroll
    for (int ks = 0; ks < NKS; ++ks) {
        const float* wr;
        if (ks < NKSA) wr = wih + (size_t)grow * KINX + ks * 32 + hi * 8;
        else           wr = whh + (size_t)grow * HH + (ks - NKSA) * 32 + hi * 8;
        const float4* p = (const float4*)wr;
        aF[ks] = pack8(p[0], p[1]);
    }

    f32x4 biasv;
    #pragma unroll
    for (int r = 0; r < 4; ++r)
        biasv[r] = bih[r * HH + jbase + hi] + bhh[r * HH + jbase + hi];

    // h-ring write slot for unit j = jbase+hi (frag coords) — validated R5-R8
    const int wksp = wv >> 3, wkhi = (wv >> 1) & 3, wel = (wv & 1) * 4 + hi;

    float cst[NCT];
    #pragma unroll
    for (int c = 0; c < NCT; ++c) cst[c] = 0.f;

    for (int s = 0; s <= TT + 1; ++s) {
        const int t = (L == 0) ? s : s - 1;
        if (t >= 0 && t < TT) {
            const bf16x8* srcA = (L == 0) ? (g_xf + (size_t)t * 2048) : g_h1f[t & 1];
            const bf16x8* srcB = (L == 0) ? g_h1f[(t + 1) & 1] : g_h2f[(t + 1) & 1];

            // ---- WG-cooperative stage: wave w stages rows ri = r*4+w
            u32x4 stg[NST];
            #pragma unroll
            for (int r = 0; r < NST; ++r) {
                const int ri = r * 4 + w;
                const int ks = ri / NCT, c = ri % NCT;
                if (r < NCXR) {   // compile-time split: x-rows are cached loads
                    stg[r] = *(const u32x4*)&srcA[(ks * 4 + ctbase + c) * 64 + lane];
                } else {          // ring rows: coherent bypass loads
                    const bf16x8* src = (ks < NKSA)
                        ? &srcA[(ks * 4 + ctbase + c) * 64 + lane]
                        : &srcB[((ks - NKSA) * 4 + ctbase + c) * 64 + lane];
                    stg[r] = ldg_cv16(src);
                }
            }
            wait_vm0();   // asm loads done; memory clobber keeps ds_writes below
            #pragma unroll
            for (int r = 0; r < NST; ++r)
                ((u32x4*)sB)[(r * 4 + w) * 64 + lane] = stg[r];
            __syncthreads();

            f32x4 acc[NCT];
            #pragma unroll
            for (int c = 0; c < NCT; ++c) acc[c] = biasv;
            #pragma unroll
            for (int ks = 0; ks < NKS; ++ks)
                #pragma unroll
                for (int c = 0; c < NCT; ++c)
                    acc[c] = __builtin_amdgcn_mfma_f32_16x16x32_bf16(
                        aF[ks], sB[(ks * NCT + c) * 64 + lane], acc[c], 0, 0, 0);

            // lane (hi,lo): gates i,f,g,o for unit j=jbase+hi, batch b=ct*16+lo
            short* ringW = (short*)((L == 0) ? g_h1f[t & 1] : g_h2f[t & 1]);
            #pragma unroll
            for (int c = 0; c < NCT; ++c) {
                const int ct = ctbase + c;
                const float gi = acc[c][0], gf = acc[c][1];
                const float gg = acc[c][2], go = acc[c][3];
                const float cn_ = sigf(gf) * cst[c] + sigf(gi) * tanh_fast(gg);
                const float hv  = sigf(go) * tanh_fast(cn_);
                cst[c] = cn_;
                stg_cv_u16(&ringW[(((wksp * 4 + ct) * 64) + wkhi * 16 + lo) * 8 + wel],
                           (unsigned)(unsigned short)f2bf(hv));
                if (t == TT - 1) {
                    const int j = jbase + hi, b = ct * 16 + lo;
                    const size_t base = (size_t)TT * BB * DOUT;
                    out[base + (size_t)L * BB * HH + (size_t)b * HH + j] = hv;
                    out[base + (size_t)2 * BB * HH + (size_t)L * BB * HH + (size_t)b * HH + j] = cn_;
                }
            }
        }
        gridbar(++ep, wg, tid);   // entry vmcnt+syncthreads also fence sB reuse
    }
}

// ---------------- output projection: 8 WGs = (odim-block, ct-pair); wave = 16 odims
__device__ void run_out(int lwg, int wg, int tid,
                        const float* __restrict__ wout, const float* __restrict__ bout,
                        float* __restrict__ out, unsigned ep, bf16x8* sB)
{
    constexpr int NKS  = HH / 32;   // 16 frag-rows
    constexpr int NST  = 8;         // 32 staged rows / 4 waves
    const int lane = tid & 63, lo = lane & 15, hi = lane >> 4;
    const int w = tid >> 6;
    const int ctbase = (lwg & 1) * 2, ob = lwg >> 1;
    const int obase = (ob * 4 + w) * 16;

    bf16x8 aF[NKS];
    #pragma unroll
    for (int ks = 0; ks < NKS; ++ks) {
        const float4* p = (const float4*)(wout + (size_t)(obase + lo) * HH + ks * 32 + hi * 8);
        aF[ks] = pack8(p[0], p[1]);
    }
    f32x4 biasv;
    #pragma unroll
    for (int r = 0; r < 4; ++r) biasv[r] = bout[obase + hi * 4 + r];

    for (int s = 0; s <= TT + 1; ++s) {
        const int t = s - 2;
        if (t >= 0 && t < TT) {
            const bf16x8* src = g_h2f[t & 1];
            u32x4 stg[NST];
            #pragma unroll
            for (int r = 0; r < NST; ++r) {
                const int ri = r * 4 + w;
                const int ks = ri >> 1, c = ri & 1;
                stg[r] = ldg_cv16(&src[(ks * 4 + ctbase + c) * 64 + lane]);
            }
            wait_vm0();
            #pragma unroll
            for (int r = 0; r < NST; ++r)
                ((u32x4*)sB)[(r * 4 + w) * 64 + lane] = stg[r];
            __syncthreads();

            f32x4 acc[2] = {biasv, biasv};
            #pragma unroll
            for (int ks = 0; ks < NKS; ++ks)
                #pragma unroll
                for (int c = 0; c < 2; ++c)
                    acc[c] = __builtin_amdgcn_mfma_f32_16x16x32_bf16(
                        aF[ks], sB[(ks * 2 + c) * 64 + lane], acc[c], 0, 0, 0);
            #pragma unroll
            for (int c = 0; c < 2; ++c)
                #pragma unroll
                for (int r = 0; r < 4; ++r) {
                    const int b = (ctbase + c) * 16 + lo, o = obase + hi * 4 + r;
                    out[(size_t)t * BB * DOUT + (size_t)b * DOUT + o] = acc[c][r];
                }
        }
        gridbar(++ep, wg, tid);
    }
}

extern "C" __global__ void __launch_bounds__(256, 1)
lstm2_fused(const float* __restrict__ x,
            const float* __restrict__ wih0, const float* __restrict__ whh0,
            const float* __restrict__ bih0, const float* __restrict__ bhh0,
            const float* __restrict__ wih1, const float* __restrict__ whh1,
            const float* __restrict__ bih1, const float* __restrict__ bhh1,
            const float* __restrict__ wout, const float* __restrict__ bout,
            float* __restrict__ out)
{
    __shared__ bf16x8 sB[3072];   // 48KB: L0 uses all, L1/OUT use 32KB

    const int tid = threadIdx.x, wg = blockIdx.x;

    const unsigned base = __hip_atomic_load(&g_epoch_base, __ATOMIC_RELAXED,
                                            __HIP_MEMORY_SCOPE_AGENT);
    unsigned ep = base;

    // init: zero t=-1 ring slots (bypass stores so bypass readers see them);
    // wg0 also arms the padding flags (monotone epochs -> replay-safe)
    {
        const int gidx = wg * 256 + tid;
        if (gidx < 4096) {
            stg_cv16(&((u32x4*)g_h1f[1])[gidx], u32x4{0, 0, 0, 0});
            stg_cv16(&((u32x4*)g_h2f[1])[gidx], u32x4{0, 0, 0, 0});
        }
        if (wg == 0 && tid < 256 - NWG_TOT)
            stg_cv_u32(&g_flags[NWG_TOT + tid], 0xFFFFFFFFu);
    }
    gridbar(++ep, wg, tid);

    if (wg < NWG_L0)
        run_layer<0, 2>(wg, wg, tid, wih0, whh0, bih0, bhh0, out, ep, sB);
    else if (wg < NWG_L0 + NWG_L1)
        run_layer<1, 1>(wg - NWG_L0, wg, tid, wih1, whh1, bih1, bhh1, out, ep, sB);
    else
        run_out(wg - NWG_L0 - NWG_L1, wg, tid, wout, bout, out, ep, sB);

    if (wg == 0 && tid == 0)
        __hip_atomic_store(&g_epoch_base, base + NBARRIERS, __ATOMIC_RELAXED,
                           __HIP_MEMORY_SCOPE_AGENT);
}

extern "C" void kernel_launch(void* const* d_in, const int* in_sizes, int n_in,
                              void* d_out, int out_size, void* d_ws, size_t ws_size,
                              hipStream_t stream) {
    const float* x    = (const float*)d_in[0];
    const float* wih0 = (const float*)d_in[1];
    const float* whh0 = (const float*)d_in[2];
    const float* bih0 = (const float*)d_in[3];
    const float* bhh0 = (const float*)d_in[4];
    const float* wih1 = (const float*)d_in[5];
    const float* whh1 = (const float*)d_in[6];
    const float* bih1 = (const float*)d_in[7];
    const float* bhh1 = (const float*)d_in[8];
    const float* wout = (const float*)d_in[9];
    const float* bout = (const float*)d_in[10];
    float* out = (float*)d_out;

    hipLaunchKernelGGL(pack_x, dim3(TT), dim3(256), 0, stream, x);
    hipLaunchKernelGGL(lstm2_fused, dim3(NWG_TOT), dim3(256), 0, stream,
                       x, wih0, whh0, bih0, bhh0, wih1, whh1, bih1, bhh1,
                       wout, bout, out);
}

// Round 11
// 5566.051 us; speedup vs baseline: 1.8938x; 1.2190x over previous
//
#include <hip/hip_runtime.h>

#define TT   1024
#define BB   64
#define DIN  256
#define HH   512
#define DOUT 256

#define NWG_L0  64
#define NWG_L1  128
#define NWG_OUT 8
#define NWG_TOT 200
#define NBARRIERS (1 + (TT + 2))

typedef short bf16x8 __attribute__((ext_vector_type(8)));
typedef float f32x4  __attribute__((ext_vector_type(4)));
typedef unsigned u32x4 __attribute__((ext_vector_type(4)));

// frag-ordered bf16 tensors: index f = ((ks*4 + ct)*64 + lane), element e
// value = M[k = ks*32 + (lane>>4)*8 + e][col = ct*16 + (lane&15)]
__device__ bf16x8 g_xf[TT * 2048];     // x packed (static, cached path)
__device__ bf16x8 g_h1f[2][4096];      // h1 ring (coherent-bypass path)
__device__ bf16x8 g_h2f[2][4096];      // h2 ring (coherent-bypass path)

// barrier state: 8 arrival counters (64B apart), never reset -> replay-safe
__device__ unsigned g_ctr[8 * 16];
__device__ unsigned g_epoch_base;

// ---------- explicitly-coherent (IF-level) memory primitives: bypass L1+L2
__device__ __forceinline__ u32x4 ldg_cv16(const void* p) {
    u32x4 r;
    asm volatile("global_load_dwordx4 %0, %1, off sc0 sc1"
                 : "=&v"(r) : "v"(p) : "memory");
    return r;
}
__device__ __forceinline__ void stg_cv16(void* p, u32x4 v) {
    asm volatile("global_store_dwordx4 %0, %1, off sc0 sc1" :: "v"(p), "v"(v) : "memory");
}
__device__ __forceinline__ void stg_cv_u16(void* p, unsigned v) {
    asm volatile("global_store_short %0, %1, off sc0 sc1" :: "v"(p), "v"(v) : "memory");
}
__device__ __forceinline__ void wait_vm0(void) {
    asm volatile("s_waitcnt vmcnt(0)" ::: "memory");
}

// ---------- low-contention grid barrier: 8-counter arrival + 1-load-per-line poll
// NWG_TOT % 8 == 0: each counter group has exactly NWG_TOT/8 = 25 members.
__device__ __forceinline__ void gridbar(unsigned e, int wg, int tid) {
    wait_vm0();                 // all this WG's bypass stores are at the coherence point
    __syncthreads();            // every wave of the WG drained
    if (tid == 0) atomicAdd(&g_ctr[(wg & 7) * 16], 1u);   // device-scope RMW at IF
    const unsigned t25 = e * 25u;
    if (tid < 64) {
        const unsigned* p = &g_ctr[(tid & 7) * 16];
        for (;;) {
            unsigned v = 0xFFFFFFFFu;
            if (tid < 8) {
                asm volatile("global_load_dword %0, %1, off sc0 sc1\n\t"
                             "s_waitcnt vmcnt(0)"
                             : "=&v"(v) : "v"(p) : "memory");
            }
            if (__all(v >= t25)) break;
            __builtin_amdgcn_s_sleep(2);
        }
    }
    __syncthreads();
}

__device__ __forceinline__ float sigf(float v) { return 1.f / (1.f + __expf(-v)); }
__device__ __forceinline__ float tanh_fast(float v) { return 2.f / (1.f + __expf(-2.f * v)) - 1.f; }

__device__ __forceinline__ short f2bf(float f) {   // RNE float->bf16 bits
    unsigned u = __builtin_bit_cast(unsigned, f);
    unsigned r = (u + 0x7FFFu + ((u >> 16) & 1u)) >> 16;
    return (short)r;
}

__device__ __forceinline__ bf16x8 pack8(float4 v0, float4 v1) {
    bf16x8 r;
    r[0] = f2bf(v0.x); r[1] = f2bf(v0.y); r[2] = f2bf(v0.z); r[3] = f2bf(v0.w);
    r[4] = f2bf(v1.x); r[5] = f2bf(v1.y); r[6] = f2bf(v1.z); r[7] = f2bf(v1.w);
    return r;
}

// ---------------- pre-pass: pack x (fp32 [T][B][DIN]) into frag-ordered bf16
extern "C" __global__ void __launch_bounds__(256)
pack_x(const float* __restrict__ x) {
    const int t = blockIdx.x, tid = threadIdx.x;
    const float* xt = x + (size_t)t * BB * DIN;
    bf16x8* dst = g_xf + (size_t)t * 2048;
    #pragma unroll
    for (int u = 0; u < 8; ++u) {
        const int f = u * 256 + tid;
        const int lane_ = f & 63, ctks = f >> 6;
        const int ct = ctks & 3, ks = ctks >> 2;
        const int b  = ct * 16 + (lane_ & 15);
        const int kb = ks * 32 + (lane_ >> 4) * 8;
        const float4* s = (const float4*)(xt + b * DIN + kb);
        dst[f] = pack8(s[0], s[1]);
    }
}

// ---------------- LSTM layer: WG = (unit-block, NCT batch-quadrants); wave = 4 units
// L=0: K=768, NCT=2 (64 WGs, x-rows cached, h-rows bypass)
// L=1: K=1024, NCT=1 (128 WGs, all rows bypass)
template<int L, int NCT>
__device__ void run_layer(int lwg, int wg, int tid,
                          const float* __restrict__ wih, const float* __restrict__ whh,
                          const float* __restrict__ bih, const float* __restrict__ bhh,
                          float* __restrict__ out, unsigned ep, bf16x8* sB)
{
    constexpr int KINX = (L == 0) ? DIN : HH;
    constexpr int NKSA = KINX / 32;          // frag-rows from first operand (8 or 16)
    constexpr int NKS  = NKSA + HH / 32;     // total frag-rows (24 or 32)
    constexpr int ROWS = NKS * NCT;          // staged rows (48 or 32)
    constexpr int NST  = ROWS / 4;           // rows staged per wave (12 or 8)
    constexpr int NCXR = (L == 0) ? (NKSA * NCT / 4) : 0;  // cached rounds (x-rows)

    const int lane = tid & 63, lo = lane & 15, hi = lane >> 4;
    const int w      = tid >> 6;
    const int ctbase = (NCT == 2) ? (lwg & 1) * 2 : (lwg & 3);
    const int ub     = (NCT == 2) ? (lwg >> 1) : (lwg >> 2);
    const int wv     = ub * 4 + w;           // unit-group [0,128)
    const int jbase  = wv * 4;
    const int grow   = (lo & 3) * HH + jbase + (lo >> 2);  // gate-major A-row for lane lo

    // --- this wave's weights as bf16 A-fragments in registers (loaded once, cached)
    bf16x8 aF[NKS];
    #pragma unroll
    for (int ks = 0; ks < NKS; ++ks) {
        const float* wr;
        if (ks < NKSA) wr = wih + (size_t)grow * KINX + ks * 32 + hi * 8;
        else           wr = whh + (size_t)grow * HH + (ks - NKSA) * 32 + hi * 8;
        const float4* p = (const float4*)wr;
        aF[ks] = pack8(p[0], p[1]);
    }

    f32x4 biasv;
    #pragma unroll
    for (int r = 0; r < 4; ++r)
        biasv[r] = bih[r * HH + jbase + hi] + bhh[r * HH + jbase + hi];

    // h-ring write slot for unit j = jbase+hi (frag coords) — validated R5-R10
    const int wksp = wv >> 3, wkhi = (wv >> 1) & 3, wel = (wv & 1) * 4 + hi;

    float cst[NCT];
    #pragma unroll
    for (int c = 0; c < NCT; ++c) cst[c] = 0.f;

    for (int s = 0; s <= TT + 1; ++s) {
        const int t = (L == 0) ? s : s - 1;
        if (t >= 0 && t < TT) {
            const bf16x8* srcA = (L == 0) ? (g_xf + (size_t)t * 2048) : g_h1f[t & 1];
            const bf16x8* srcB = (L == 0) ? g_h1f[(t + 1) & 1] : g_h2f[(t + 1) & 1];

            // ---- WG-cooperative stage: wave w stages rows ri = r*4+w
            u32x4 stg[NST];
            #pragma unroll
            for (int r = 0; r < NST; ++r) {
                const int ri = r * 4 + w;
                const int ks = ri / NCT, c = ri % NCT;
                if (r < NCXR) {   // compile-time split: x-rows are cached loads
                    stg[r] = *(const u32x4*)&srcA[(ks * 4 + ctbase + c) * 64 + lane];
                } else {          // ring rows: coherent bypass loads
                    const bf16x8* src = (ks < NKSA)
                        ? &srcA[(ks * 4 + ctbase + c) * 64 + lane]
                        : &srcB[((ks - NKSA) * 4 + ctbase + c) * 64 + lane];
                    stg[r] = ldg_cv16(src);
                }
            }
            wait_vm0();   // asm loads done; memory clobber keeps ds_writes below
            #pragma unroll
            for (int r = 0; r < NST; ++r)
                ((u32x4*)sB)[(r * 4 + w) * 64 + lane] = stg[r];
            __syncthreads();

            f32x4 acc[NCT];
            #pragma unroll
            for (int c = 0; c < NCT; ++c) acc[c] = biasv;
            #pragma unroll
            for (int ks = 0; ks < NKS; ++ks)
                #pragma unroll
                for (int c = 0; c < NCT; ++c)
                    acc[c] = __builtin_amdgcn_mfma_f32_16x16x32_bf16(
                        aF[ks], sB[(ks * NCT + c) * 64 + lane], acc[c], 0, 0, 0);

            // lane (hi,lo): gates i,f,g,o for unit j=jbase+hi, batch b=ct*16+lo
            short* ringW = (short*)((L == 0) ? g_h1f[t & 1] : g_h2f[t & 1]);
            #pragma unroll
            for (int c = 0; c < NCT; ++c) {
                const int ct = ctbase + c;
                const float gi = acc[c][0], gf = acc[c][1];
                const float gg = acc[c][2], go = acc[c][3];
                const float cn_ = sigf(gf) * cst[c] + sigf(gi) * tanh_fast(gg);
                const float hv  = sigf(go) * tanh_fast(cn_);
                cst[c] = cn_;
                stg_cv_u16(&ringW[(((wksp * 4 + ct) * 64) + wkhi * 16 + lo) * 8 + wel],
                           (unsigned)(unsigned short)f2bf(hv));
                if (t == TT - 1) {
                    const int j = jbase + hi, b = ct * 16 + lo;
                    const size_t base = (size_t)TT * BB * DOUT;
                    out[base + (size_t)L * BB * HH + (size_t)b * HH + j] = hv;
                    out[base + (size_t)2 * BB * HH + (size_t)L * BB * HH + (size_t)b * HH + j] = cn_;
                }
            }
        }
        gridbar(++ep, wg, tid);   // entry vmcnt+syncthreads also fence sB reuse
    }
}

// ---------------- output projection: 8 WGs = (odim-block, ct-pair); wave = 16 odims
__device__ void run_out(int lwg, int wg, int tid,
                        const float* __restrict__ wout, const float* __restrict__ bout,
                        float* __restrict__ out, unsigned ep, bf16x8* sB)
{
    constexpr int NKS  = HH / 32;   // 16 frag-rows
    constexpr int NST  = 8;         // 32 staged rows / 4 waves
    const int lane = tid & 63, lo = lane & 15, hi = lane >> 4;
    const int w = tid >> 6;
    const int ctbase = (lwg & 1) * 2, ob = lwg >> 1;
    const int obase = (ob * 4 + w) * 16;

    bf16x8 aF[NKS];
    #pragma unroll
    for (int ks = 0; ks < NKS; ++ks) {
        const float4* p = (const float4*)(wout + (size_t)(obase + lo) * HH + ks * 32 + hi * 8);
        aF[ks] = pack8(p[0], p[1]);
    }
    f32x4 biasv;
    #pragma unroll
    for (int r = 0; r < 4; ++r) biasv[r] = bout[obase + hi * 4 + r];

    for (int s = 0; s <= TT + 1; ++s) {
        const int t = s - 2;
        if (t >= 0 && t < TT) {
            const bf16x8* src = g_h2f[t & 1];
            u32x4 stg[NST];
            #pragma unroll
            for (int r = 0; r < NST; ++r) {
                const int ri = r * 4 + w;
                const int ks = ri >> 1, c = ri & 1;
                stg[r] = ldg_cv16(&src[(ks * 4 + ctbase + c) * 64 + lane]);
            }
            wait_vm0();
            #pragma unroll
            for (int r = 0; r < NST; ++r)
                ((u32x4*)sB)[(r * 4 + w) * 64 + lane] = stg[r];
            __syncthreads();

            f32x4 acc[2] = {biasv, biasv};
            #pragma unroll
            for (int ks = 0; ks < NKS; ++ks)
                #pragma unroll
                for (int c = 0; c < 2; ++c)
                    acc[c] = __builtin_amdgcn_mfma_f32_16x16x32_bf16(
                        aF[ks], sB[(ks * 2 + c) * 64 + lane], acc[c], 0, 0, 0);
            #pragma unroll
            for (int c = 0; c < 2; ++c)
                #pragma unroll
                for (int r = 0; r < 4; ++r) {
                    const int b = (ctbase + c) * 16 + lo, o = obase + hi * 4 + r;
                    out[(size_t)t * BB * DOUT + (size_t)b * DOUT + o] = acc[c][r];
                }
        }
        gridbar(++ep, wg, tid);
    }
}

extern "C" __global__ void __launch_bounds__(256, 1)
lstm2_fused(const float* __restrict__ x,
            const float* __restrict__ wih0, const float* __restrict__ whh0,
            const float* __restrict__ bih0, const float* __restrict__ bhh0,
            const float* __restrict__ wih1, const float* __restrict__ whh1,
            const float* __restrict__ bih1, const float* __restrict__ bhh1,
            const float* __restrict__ wout, const float* __restrict__ bout,
            float* __restrict__ out)
{
    __shared__ bf16x8 sB[3072];   // 48KB: L0 uses all, L1/OUT use 32KB

    const int tid = threadIdx.x, wg = blockIdx.x;

    const unsigned base = __hip_atomic_load(&g_epoch_base, __ATOMIC_RELAXED,
                                            __HIP_MEMORY_SCOPE_AGENT);
    unsigned ep = base;

    // init: zero t=-1 ring slots (bypass stores so bypass readers see them)
    {
        const int gidx = wg * 256 + tid;
        if (gidx < 4096) {
            stg_cv16(&((u32x4*)g_h1f[1])[gidx], u32x4{0, 0, 0, 0});
            stg_cv16(&((u32x4*)g_h2f[1])[gidx], u32x4{0, 0, 0, 0});
        }
    }
    gridbar(++ep, wg, tid);

    if (wg < NWG_L0)
        run_layer<0, 2>(wg, wg, tid, wih0, whh0, bih0, bhh0, out, ep, sB);
    else if (wg < NWG_L0 + NWG_L1)
        run_layer<1, 1>(wg - NWG_L0, wg, tid, wih1, whh1, bih1, bhh1, out, ep, sB);
    else
        run_out(wg - NWG_L0 - NWG_L1, wg, tid, wout, bout, out, ep, sB);

    if (wg == 0 && tid == 0)
        __hip_atomic_store(&g_epoch_base, base + NBARRIERS, __ATOMIC_RELAXED,
                           __HIP_MEMORY_SCOPE_AGENT);
}

extern "C" void kernel_launch(void* const* d_in, const int* in_sizes, int n_in,
                              void* d_out, int out_size, void* d_ws, size_t ws_size,
                              hipStream_t stream) {
    const float* x    = (const float*)d_in[0];
    const float* wih0 = (const float*)d_in[1];
    const float* whh0 = (const float*)d_in[2];
    const float* bih0 = (const float*)d_in[3];
    const float* bhh0 = (const float*)d_in[4];
    const float* wih1 = (const float*)d_in[5];
    const float* whh1 = (const float*)d_in[6];
    const float* bih1 = (const float*)d_in[7];
    const float* bhh1 = (const float*)d_in[8];
    const float* wout = (const float*)d_in[9];
    const float* bout = (const float*)d_in[10];
    float* out = (float*)d_out;

    hipLaunchKernelGGL(pack_x, dim3(TT), dim3(256), 0, stream, x);
    hipLaunchKernelGGL(lstm2_fused, dim3(NWG_TOT), dim3(256), 0, stream,
                       x, wih0, whh0, bih0, bhh0, wih1, whh1, bih1, bhh1,
                       wout, bout, out);
}

// Round 12
// 4483.461 us; speedup vs baseline: 2.3511x; 1.2415x over previous
//
#include <hip/hip_runtime.h>

#define TT   1024
#define BB   64
#define DIN  256
#define HH   512
#define DOUT 256

#define NWG_L0  64
#define NWG_L1  128
#define NWG_OUT 8
#define NWG_TOT 200

typedef short bf16x8 __attribute__((ext_vector_type(8)));
typedef float f32x4  __attribute__((ext_vector_type(4)));
typedef unsigned u32x4 __attribute__((ext_vector_type(4)));

// frag-ordered bf16 tensors: index f = ((ks*4 + ct)*64 + lane), element e
// value = M[k = ks*32 + (lane>>4)*8 + e][col = ct*16 + (lane&15)]
__device__ bf16x8 g_xf[TT * 2048];     // x packed (static, cached path)
__device__ bf16x8 g_h1f[4][4096];      // h1 ring, 4 slots (coherent-bypass path)
__device__ bf16x8 g_h2f[4][4096];      // h2 ring, 4 slots
__device__ bf16x8 g_h1z[4096];         // t=-1 zeros (never written)
__device__ bf16x8 g_h2z[4096];

// p2p sync: kind(0 cp_h1, 1 cp_h2, 2 cd_h1, 3 cd_h2) x ct(4) x slot(4); 64B apart.
// Monotone, never reset; per launch: cp_* += 32*256, cd_h1 += 64*256, cd_h2 += 36*256.
__device__ unsigned g_sync[4 * 4 * 4 * 16];
__device__ unsigned g_iter;

__device__ __forceinline__ unsigned* syncp(int kind, int ct, int slot) {
    return &g_sync[(((kind * 4) + ct) * 4 + slot) * 16];
}

// ---------- explicitly-coherent (IF-level) primitives: bypass L1+L2
__device__ __forceinline__ u32x4 ldg_cv16(const void* p) {
    u32x4 r;
    asm volatile("global_load_dwordx4 %0, %1, off sc0 sc1"
                 : "=&v"(r) : "v"(p) : "memory");
    return r;
}
__device__ __forceinline__ void stg_cv_u16(void* p, unsigned v) {
    asm volatile("global_store_short %0, %1, off sc0 sc1" :: "v"(p), "v"(v) : "memory");
}
__device__ __forceinline__ void wait_vm0(void) {
    asm volatile("s_waitcnt vmcnt(0)" ::: "memory");
}

// ---------- lane-parallel counter wait: wave0 lanes poll (ptr,target), then WG proceeds
__device__ __forceinline__ void waitpoll(const unsigned* p, unsigned tgt, int active, int tid) {
    if (tid < 64) {
        for (;;) {
            unsigned v = 0xFFFFFFFFu;
            if (active)
                asm volatile("global_load_dword %0, %1, off sc0 sc1\n\t"
                             "s_waitcnt vmcnt(0)"
                             : "=&v"(v) : "v"(p) : "memory");
            if (__all(v >= tgt)) break;   // inactive lanes: v=~0 always passes
            __builtin_amdgcn_s_sleep(1);
        }
    }
    __syncthreads();
}

__device__ __forceinline__ float sigf(float v) { return 1.f / (1.f + __expf(-v)); }
__device__ __forceinline__ float tanh_fast(float v) { return 2.f / (1.f + __expf(-2.f * v)) - 1.f; }

__device__ __forceinline__ short f2bf(float f) {   // RNE float->bf16 bits
    unsigned u = __builtin_bit_cast(unsigned, f);
    unsigned r = (u + 0x7FFFu + ((u >> 16) & 1u)) >> 16;
    return (short)r;
}

__device__ __forceinline__ bf16x8 pack8(float4 v0, float4 v1) {
    bf16x8 r;
    r[0] = f2bf(v0.x); r[1] = f2bf(v0.y); r[2] = f2bf(v0.z); r[3] = f2bf(v0.w);
    r[4] = f2bf(v1.x); r[5] = f2bf(v1.y); r[6] = f2bf(v1.z); r[7] = f2bf(v1.w);
    return r;
}

// ---------------- pre-pass: pack x (fp32 [T][B][DIN]) into frag-ordered bf16
extern "C" __global__ void __launch_bounds__(256)
pack_x(const float* __restrict__ x) {
    const int t = blockIdx.x, tid = threadIdx.x;
    const float* xt = x + (size_t)t * BB * DIN;
    bf16x8* dst = g_xf + (size_t)t * 2048;
    #pragma unroll
    for (int u = 0; u < 8; ++u) {
        const int f = u * 256 + tid;
        const int lane_ = f & 63, ctks = f >> 6;
        const int ct = ctks & 3, ks = ctks >> 2;
        const int b  = ct * 16 + (lane_ & 15);
        const int kb = ks * 32 + (lane_ >> 4) * 8;
        const float4* s = (const float4*)(xt + b * DIN + kb);
        dst[f] = pack8(s[0], s[1]);
    }
}

// ---------------- LSTM layer: WG = (unit-block, NCT batch-quadrants); wave = 4 units
// L=0: K=768, NCT=2 (64 WGs); L=1: K=1024, NCT=1 (128 WGs). p2p-synced.
template<int L, int NCT>
__device__ void run_layer(int lwg, int tid,
                          const float* __restrict__ wih, const float* __restrict__ whh,
                          const float* __restrict__ bih, const float* __restrict__ bhh,
                          float* __restrict__ out, unsigned Q, bf16x8* sB)
{
    constexpr int KINX = (L == 0) ? DIN : HH;
    constexpr int NKSA = KINX / 32;          // frag-rows from first operand (8 or 16)
    constexpr int NKS  = NKSA + HH / 32;     // total frag-rows (24 or 32)
    constexpr int ROWS = NKS * NCT;          // staged rows (48 or 32)
    constexpr int NST  = ROWS / 4;           // rows staged per wave (12 or 8)
    constexpr int NCXR = (L == 0) ? (NKSA * NCT / 4) : 0;  // cached rounds (x-rows)

    const int lane = tid & 63, lo = lane & 15, hi = lane >> 4;
    const int w      = tid >> 6;
    const int ctbase = (NCT == 2) ? (lwg & 1) * 2 : (lwg & 3);
    const int ub     = (NCT == 2) ? (lwg >> 1) : (lwg >> 2);
    const int wv     = ub * 4 + w;           // unit-group [0,128)
    const int jbase  = wv * 4;
    const int grow   = (lo & 3) * HH + jbase + (lo >> 2);  // gate-major A-row for lane lo

    // --- this wave's weights as bf16 A-fragments in registers (loaded once, cached)
    bf16x8 aF[NKS];
    #pragma unroll
    for (int ks = 0; ks < NKS; ++ks) {
        const float* wr;
        if (ks < NKSA) wr = wih + (size_t)grow * KINX + ks * 32 + hi * 8;
        else           wr = whh + (size_t)grow * HH + (ks - NKSA) * 32 + hi * 8;
        const float4* p = (const float4*)wr;
        aF[ks] = pack8(p[0], p[1]);
    }

    f32x4 biasv;
    #pragma unroll
    for (int r = 0; r < 4; ++r)
        biasv[r] = bih[r * HH + jbase + hi] + bhh[r * HH + jbase + hi];

    // h-ring write slot for unit j = jbase+hi (frag coords) — validated R5-R11
    const int wksp = wv >> 3, wkhi = (wv >> 1) & 3, wel = (wv & 1) * 4 + hi;

    const unsigned cpb = Q * 8192u;          // cp_* launch base (32*256)
    float cst[NCT];
    #pragma unroll
    for (int c = 0; c < NCT; ++c) cst[c] = 0.f;

    for (int t = 0; t < TT; ++t) {
        // ---- waits (lane-parallel): producers ready + own slot free
        const unsigned* wp = syncp(0, 0, 0); unsigned wt = 0; int wa = 0;
        if (L == 0) {
            if (lane < 2) {             // h1[t-1] produced (32 L0-ct WGs)
                if (t > 0) { wp = syncp(0, ctbase + lane, (t - 1) & 3);
                             wt = cpb + 32u * (((t - 1) >> 2) + 1); wa = 1; }
            } else if (lane < 4) {      // slot free: h1[t-4] consumed by 64
                if (t >= 4) { wp = syncp(2, ctbase + lane - 2, t & 3);
                              wt = Q * 16384u + 64u * (((t - 4) >> 2) + 1); wa = 1; }
            }
        } else {
            if (lane == 0) { wp = syncp(0, ctbase, t & 3);            // h1[t] ready
                             wt = cpb + 32u * ((t >> 2) + 1); wa = 1; }
            else if (lane == 1) { if (t > 0) { wp = syncp(1, ctbase, (t - 1) & 3);
                                               wt = cpb + 32u * (((t - 1) >> 2) + 1); wa = 1; } }
            else if (lane == 2) { if (t >= 4) { wp = syncp(3, ctbase, t & 3);   // slot free (36)
                                                wt = Q * 9216u + 36u * (((t - 4) >> 2) + 1); wa = 1; } }
        }
        waitpoll(wp, wt, wa, tid);

        const bf16x8* srcA = (L == 0) ? (g_xf + (size_t)t * 2048) : g_h1f[t & 3];
        const bf16x8* srcB = (L == 0) ? ((t == 0) ? g_h1z : g_h1f[(t - 1) & 3])
                                      : ((t == 0) ? g_h2z : g_h2f[(t - 1) & 3]);

        // ---- WG-cooperative stage: wave w stages rows ri = r*4+w
        u32x4 stg[NST];
        #pragma unroll
        for (int r = 0; r < NST; ++r) {
            const int ri = r * 4 + w;
            const int ks = ri / NCT, c = ri % NCT;
            if (r < NCXR) {   // compile-time split: x-rows are cached loads
                stg[r] = *(const u32x4*)&srcA[(ks * 4 + ctbase + c) * 64 + lane];
            } else {          // ring rows: coherent bypass loads
                const bf16x8* src = (ks < NKSA)
                    ? &srcA[(ks * 4 + ctbase + c) * 64 + lane]
                    : &srcB[((ks - NKSA) * 4 + ctbase + c) * 64 + lane];
                stg[r] = ldg_cv16(src);
            }
        }
        wait_vm0();
        #pragma unroll
        for (int r = 0; r < NST; ++r)
            ((u32x4*)sB)[(r * 4 + w) * 64 + lane] = stg[r];
        __syncthreads();      // all waves' loads landed + LDS visible

        // ---- consumed signals (fire & forget)
        if (L == 0) {
            if (t > 0 && tid < 2) atomicAdd(syncp(2, ctbase + tid, (t - 1) & 3), 1u);
        } else {
            if (tid == 0) atomicAdd(syncp(2, ctbase, t & 3), 1u);
            if (tid == 1 && t > 0) atomicAdd(syncp(3, ctbase, (t - 1) & 3), 1u);
        }

        f32x4 acc[NCT];
        #pragma unroll
        for (int c = 0; c < NCT; ++c) acc[c] = biasv;
        #pragma unroll
        for (int ks = 0; ks < NKS; ++ks)
            #pragma unroll
            for (int c = 0; c < NCT; ++c)
                acc[c] = __builtin_amdgcn_mfma_f32_16x16x32_bf16(
                    aF[ks], sB[(ks * NCT + c) * 64 + lane], acc[c], 0, 0, 0);

        // lane (hi,lo): gates i,f,g,o for unit j=jbase+hi, batch b=ct*16+lo
        short* ringW = (short*)((L == 0) ? g_h1f[t & 3] : g_h2f[t & 3]);
        #pragma unroll
        for (int c = 0; c < NCT; ++c) {
            const int ct = ctbase + c;
            const float gi = acc[c][0], gf = acc[c][1];
            const float gg = acc[c][2], go = acc[c][3];
            const float cn_ = sigf(gf) * cst[c] + sigf(gi) * tanh_fast(gg);
            const float hv  = sigf(go) * tanh_fast(cn_);
            cst[c] = cn_;
            stg_cv_u16(&ringW[(((wksp * 4 + ct) * 64) + wkhi * 16 + lo) * 8 + wel],
                       (unsigned)(unsigned short)f2bf(hv));
            if (t == TT - 1) {
                const int j = jbase + hi, b = ct * 16 + lo;
                const size_t base = (size_t)TT * BB * DOUT;
                out[base + (size_t)L * BB * HH + (size_t)b * HH + j] = hv;
                out[base + (size_t)2 * BB * HH + (size_t)L * BB * HH + (size_t)b * HH + j] = cn_;
            }
        }
        wait_vm0();           // ring stores at coherence point
        __syncthreads();      // all waves drained
        if (L == 0) { if (tid < 2) atomicAdd(syncp(0, ctbase + tid, t & 3), 1u); }
        else        { if (tid == 0) atomicAdd(syncp(1, ctbase, t & 3), 1u); }
    }
    // dummy consumed-signals for the final h (keeps per-slot counts uniform)
    if (L == 0) { if (tid < 2) atomicAdd(syncp(2, ctbase + tid, 3), 1u); }
    else        { if (tid == 0) atomicAdd(syncp(3, ctbase, 3), 1u); }
}

// ---------------- output projection: 8 WGs = (odim-block, ct-pair); wave = 16 odims
__device__ void run_out(int lwg, int tid,
                        const float* __restrict__ wout, const float* __restrict__ bout,
                        float* __restrict__ out, unsigned Q, bf16x8* sB)
{
    constexpr int NKS  = HH / 32;   // 16 frag-rows
    constexpr int NST  = 8;         // 32 staged rows / 4 waves
    const int lane = tid & 63, lo = lane & 15, hi = lane >> 4;
    const int w = tid >> 6;
    const int ctbase = (lwg & 1) * 2, ob = lwg >> 1;
    const int obase = (ob * 4 + w) * 16;
    const unsigned cpb = Q * 8192u;

    bf16x8 aF[NKS];
    #pragma unroll
    for (int ks = 0; ks < NKS; ++ks) {
        const float4* p = (const float4*)(wout + (size_t)(obase + lo) * HH + ks * 32 + hi * 8);
        aF[ks] = pack8(p[0], p[1]);
    }
    f32x4 biasv;
    #pragma unroll
    for (int r = 0; r < 4; ++r) biasv[r] = bout[obase + hi * 4 + r];

    for (int t = 0; t < TT; ++t) {
        const unsigned* wp = syncp(0, 0, 0); unsigned wt = 0; int wa = 0;
        if (lane < 2) { wp = syncp(1, ctbase + lane, t & 3);
                        wt = cpb + 32u * ((t >> 2) + 1); wa = 1; }
        waitpoll(wp, wt, wa, tid);

        const bf16x8* src = g_h2f[t & 3];
        u32x4 stg[NST];
        #pragma unroll
        for (int r = 0; r < NST; ++r) {
            const int ri = r * 4 + w;
            const int ks = ri >> 1, c = ri & 1;
            stg[r] = ldg_cv16(&src[(ks * 4 + ctbase + c) * 64 + lane]);
        }
        wait_vm0();
        #pragma unroll
        for (int r = 0; r < NST; ++r)
            ((u32x4*)sB)[(r * 4 + w) * 64 + lane] = stg[r];
        __syncthreads();
        if (tid < 2) atomicAdd(syncp(3, ctbase + tid, t & 3), 1u);

        f32x4 acc[2] = {biasv, biasv};
        #pragma unroll
        for (int ks = 0; ks < NKS; ++ks)
            #pragma unroll
            for (int c = 0; c < 2; ++c)
                acc[c] = __builtin_amdgcn_mfma_f32_16x16x32_bf16(
                    aF[ks], sB[(ks * 2 + c) * 64 + lane], acc[c], 0, 0, 0);
        #pragma unroll
        for (int c = 0; c < 2; ++c)
            #pragma unroll
            for (int r = 0; r < 4; ++r) {
                const int b = (ctbase + c) * 16 + lo, o = obase + hi * 4 + r;
                out[(size_t)t * BB * DOUT + (size_t)b * DOUT + o] = acc[c][r];
            }
    }
}

extern "C" __global__ void __launch_bounds__(256, 1)
lstm2_fused(const float* __restrict__ x,
            const float* __restrict__ wih0, const float* __restrict__ whh0,
            const float* __restrict__ bih0, const float* __restrict__ bhh0,
            const float* __restrict__ wih1, const float* __restrict__ whh1,
            const float* __restrict__ bih1, const float* __restrict__ bhh1,
            const float* __restrict__ wout, const float* __restrict__ bout,
            float* __restrict__ out)
{
    __shared__ bf16x8 sB[3072];   // 48KB: L0 uses all, L1/OUT use 32KB

    const int tid = threadIdx.x, wg = blockIdx.x;
    const unsigned Q = __hip_atomic_load(&g_iter, __ATOMIC_RELAXED, __HIP_MEMORY_SCOPE_AGENT);

    if (wg < NWG_L0)
        run_layer<0, 2>(wg, tid, wih0, whh0, bih0, bhh0, out, Q, sB);
    else if (wg < NWG_L0 + NWG_L1)
        run_layer<1, 1>(wg - NWG_L0, tid, wih1, whh1, bih1, bhh1, out, Q, sB);
    else
        run_out(wg - NWG_L0 - NWG_L1, tid, wout, bout, out, Q, sB);

    // wg0 (an L0 WG) can only exit after the whole pipeline drained past t~1019,
    // so every WG has long since read Q -> safe to advance for the next replay.
    if (wg == 0 && tid == 0)
        __hip_atomic_store(&g_iter, Q + 1, __ATOMIC_RELAXED, __HIP_MEMORY_SCOPE_AGENT);
}

extern "C" void kernel_launch(void* const* d_in, const int* in_sizes, int n_in,
                              void* d_out, int out_size, void* d_ws, size_t ws_size,
                              hipStream_t stream) {
    const float* x    = (const float*)d_in[0];
    const float* wih0 = (const float*)d_in[1];
    const float* whh0 = (const float*)d_in[2];
    const float* bih0 = (const float*)d_in[3];
    const float* bhh0 = (const float*)d_in[4];
    const float* wih1 = (const float*)d_in[5];
    const float* whh1 = (const float*)d_in[6];
    const float* bih1 = (const float*)d_in[7];
    const float* bhh1 = (const float*)d_in[8];
    const float* wout = (const float*)d_in[9];
    const float* bout = (const float*)d_in[10];
    float* out = (float*)d_out;

    hipLaunchKernelGGL(pack_x, dim3(TT), dim3(256), 0, stream, x);
    hipLaunchKernelGGL(lstm2_fused, dim3(NWG_TOT), dim3(256), 0, stream,
                       x, wih0, whh0, bih0, bhh0, wih1, whh1, bih1, bhh1,
                       wout, bout, out);
}

// Round 14
// 3857.787 us; speedup vs baseline: 2.7324x; 1.1622x over previous
//
#include <hip/hip_runtime.h>

#define TT   1024
#define BB   64
#define DIN  256
#define HH   512
#define DOUT 256

#define NWG_L0  64
#define NWG_L1  128
#define NWG_OUT 8
#define NWG_TOT 200

typedef short bf16x8 __attribute__((ext_vector_type(8)));
typedef float f32x4  __attribute__((ext_vector_type(4)));
typedef unsigned u32x4 __attribute__((ext_vector_type(4)));

// frag-ordered bf16 tensors: index f = ((ks*4 + ct)*64 + lane), element e
// value = M[k = ks*32 + (lane>>4)*8 + e][col = ct*16 + (lane&15)]
__device__ bf16x8 g_xf[TT * 2048];     // x packed (static, cached path)
__device__ bf16x8 g_h1f[4][4096];      // h1 ring, 4 slots (coherent-bypass path)
__device__ bf16x8 g_h2f[4][4096];      // h2 ring, 4 slots
__device__ bf16x8 g_h1z[4096];         // t=-1 zeros (never written)
__device__ bf16x8 g_h2z[4096];

// per-producer/per-consumer progress flags, one 64B line each, monotone values
// V = Q*2048 + t + 1 (never reset -> replay-safe). NO atomics anywhere.
// layout (line index):
//   fp1  [p(2)][ub(32)]   : 0   + p*32+ub    h1 slot-ready, L0 producer (quadrants 2p,2p+1)
//   fp2  [ct(4)][ub2(32)] : 64  + ct*32+ub2  h2 slot-ready, L1 producer
//   fc1L1[ct(4)][ub2(32)] : 192 + ct*32+ub2  L1 consumed h1[t]   (posts Qb+t+1)
//   fc1L0[p(2)][ub(32)]   : 320 + p*32+ub    L0 consumed h1[t-1] (posts Qb+t)
//   fc2L1[ct(4)][ub2(32)] : 384 + ct*32+ub2  L1 consumed h2[t-1] (posts Qb+t)
//   fc2OUT[cp(2)*4+ob(4)] : 512 + cp*4+ob    OUT consumed h2[t]  (posts Qb+t+1)
__device__ unsigned g_flg[520 * 16];
__device__ unsigned g_iter;

__device__ __forceinline__ unsigned* FLG(int idx) { return &g_flg[idx * 16]; }

// ---------- explicitly-coherent (IF-level) primitives: bypass L1+L2
__device__ __forceinline__ u32x4 ldg_cv16(const void* p) {
    u32x4 r;
    asm volatile("global_load_dwordx4 %0, %1, off sc0 sc1"
                 : "=&v"(r) : "v"(p) : "memory");
    return r;
}
__device__ __forceinline__ void stg_cv_u16(void* p, unsigned v) {
    asm volatile("global_store_short %0, %1, off sc0 sc1" :: "v"(p), "v"(v) : "memory");
}
__device__ __forceinline__ void stg_cv_u32(void* p, unsigned v) {
    asm volatile("global_store_dword %0, %1, off sc0 sc1" :: "v"(p), "v"(v) : "memory");
}
__device__ __forceinline__ void wait_vm0(void) {
    asm volatile("s_waitcnt vmcnt(0)" ::: "memory");
}

// ---------- lane-parallel flag wait. UNSIGNED compare: inactive lanes hold ~0
// (always passes); values are monotone within a session, no wrap (R13 bug fixed).
__device__ __forceinline__ void waitpoll(const unsigned* p, unsigned tgt, int active, int tid) {
    for (;;) {
        unsigned v = 0xFFFFFFFFu;
        if (active)
            asm volatile("global_load_dword %0, %1, off sc0 sc1\n\t"
                         "s_waitcnt vmcnt(0)"
                         : "=&v"(v) : "v"(p) : "memory");
        if (__all(v >= tgt)) break;
        __builtin_amdgcn_s_sleep(1);
    }
    __syncthreads();
}

__device__ __forceinline__ float sigf(float v) { return 1.f / (1.f + __expf(-v)); }
__device__ __forceinline__ float tanh_fast(float v) { return 2.f / (1.f + __expf(-2.f * v)) - 1.f; }

__device__ __forceinline__ short f2bf(float f) {   // RNE float->bf16 bits
    unsigned u = __builtin_bit_cast(unsigned, f);
    unsigned r = (u + 0x7FFFu + ((u >> 16) & 1u)) >> 16;
    return (short)r;
}

__device__ __forceinline__ bf16x8 pack8(float4 v0, float4 v1) {
    bf16x8 r;
    r[0] = f2bf(v0.x); r[1] = f2bf(v0.y); r[2] = f2bf(v0.z); r[3] = f2bf(v0.w);
    r[4] = f2bf(v1.x); r[5] = f2bf(v1.y); r[6] = f2bf(v1.z); r[7] = f2bf(v1.w);
    return r;
}

// ---------------- pre-pass: pack x (fp32 [T][B][DIN]) into frag-ordered bf16
extern "C" __global__ void __launch_bounds__(256)
pack_x(const float* __restrict__ x) {
    const int t = blockIdx.x, tid = threadIdx.x;
    const float* xt = x + (size_t)t * BB * DIN;
    bf16x8* dst = g_xf + (size_t)t * 2048;
    #pragma unroll
    for (int u = 0; u < 8; ++u) {
        const int f = u * 256 + tid;
        const int lane_ = f & 63, ctks = f >> 6;
        const int ct = ctks & 3, ks = ctks >> 2;
        const int b  = ct * 16 + (lane_ & 15);
        const int kb = ks * 32 + (lane_ >> 4) * 8;
        const float4* s = (const float4*)(xt + b * DIN + kb);
        dst[f] = pack8(s[0], s[1]);
    }
}

// ---------------- LSTM layer: WG = (unit-block, NCT batch-quadrants); wave = 4 units
// L=0: K=768, NCT=2 (64 WGs = ub(32) x p(2)); L=1: K=1024, NCT=1 (128 WGs = ub2(32) x ct(4))
template<int L, int NCT>
__device__ void run_layer(int lwg, int tid,
                          const float* __restrict__ wih, const float* __restrict__ whh,
                          const float* __restrict__ bih, const float* __restrict__ bhh,
                          float* __restrict__ out, unsigned Q, bf16x8* sB)
{
    constexpr int KINX = (L == 0) ? DIN : HH;
    constexpr int NKSA = KINX / 32;          // frag-rows from first operand (8 or 16)
    constexpr int NKS  = NKSA + HH / 32;     // total frag-rows (24 or 32)
    constexpr int ROWS = NKS * NCT;          // staged rows (48 or 32)
    constexpr int NST  = ROWS / 4;           // rows staged per wave (12 or 8)
    constexpr int NCXR = (L == 0) ? (NKSA * NCT / 4) : 0;  // cached rounds (x-rows)

    const int lane = tid & 63, lo = lane & 15, hi = lane >> 4;
    const int w      = tid >> 6;
    const int ctbase = (NCT == 2) ? (lwg & 1) * 2 : (lwg & 3);
    const int grp    = (NCT == 2) ? (lwg & 1) : (lwg & 3);        // p or ct
    const int ub     = (NCT == 2) ? (lwg >> 1) : (lwg >> 2);      // 0..31
    const int wv     = ub * 4 + w;           // unit-group [0,128)
    const int jbase  = wv * 4;
    const int grow   = (lo & 3) * HH + jbase + (lo >> 2);  // gate-major A-row for lane lo

    // --- this wave's weights as bf16 A-fragments in registers (loaded once, cached)
    bf16x8 aF[NKS];
    #pragma unroll
    for (int ks = 0; ks < NKS; ++ks) {
        const float* wr;
        if (ks < NKSA) wr = wih + (size_t)grow * KINX + ks * 32 + hi * 8;
        else           wr = whh + (size_t)grow * HH + (ks - NKSA) * 32 + hi * 8;
        const float4* p = (const float4*)wr;
        aF[ks] = pack8(p[0], p[1]);
    }

    f32x4 biasv;
    #pragma unroll
    for (int r = 0; r < 4; ++r)
        biasv[r] = bih[r * HH + jbase + hi] + bhh[r * HH + jbase + hi];

    // h-ring write slot for unit j = jbase+hi (frag coords) — validated R5-R12
    const int wksp = wv >> 3, wkhi = (wv >> 1) & 3, wel = (wv & 1) * 4 + hi;

    const unsigned Qb = Q * 2048u;
    float cst[NCT];
    #pragma unroll
    for (int c = 0; c < NCT; ++c) cst[c] = 0.f;

    for (int t = 0; t < TT; ++t) {
        // ---- waits: all producer-ready + slot-free flags polled lane-parallel
        const unsigned* wp = g_flg; unsigned wt = 0; int wa = 0;
        if (L == 0) {
            if (w == 0) {            // h1[t-1] ready: 32 L0 producers of pair grp
                if (lane < 32 && t >= 1) { wp = FLG(0 + grp * 32 + lane); wt = Qb + t; wa = 1; }
            } else if (w == 1) {     // slot free: L1 consumers of h1[t-4], quadrants 2p,2p+1
                if (t >= 4) { wp = FLG(192 + (grp * 2 + (lane >> 5)) * 32 + (lane & 31));
                              wt = Qb + t - 3; wa = 1; }
            } else if (w == 2) {     // slot free: L0 consumers (pair grp)
                if (lane < 32 && t >= 4) { wp = FLG(320 + grp * 32 + lane);
                                           wt = Qb + t - 3; wa = 1; }
            }
        } else {
            if (w == 0) {
                if (lane < 32) {     // h1[t] ready
                    wp = FLG(0 + (grp >> 1) * 32 + lane); wt = Qb + t + 1; wa = 1;
                } else if (t >= 1) { // h2[t-1] ready
                    wp = FLG(64 + grp * 32 + (lane - 32)); wt = Qb + t; wa = 1;
                }
            } else if (w == 1 && t >= 4) {   // slot free: consumers of h2[t-4][ct]
                if (lane < 32)      { wp = FLG(384 + grp * 32 + lane); wt = Qb + t - 3; wa = 1; }
                else if (lane < 36) { wp = FLG(512 + (grp >> 1) * 4 + (lane - 32));
                                      wt = Qb + t - 3; wa = 1; }
            }
        }
        waitpoll(wp, wt, wa, tid);

        const bf16x8* srcA = (L == 0) ? (g_xf + (size_t)t * 2048) : g_h1f[t & 3];
        const bf16x8* srcB = (L == 0) ? ((t == 0) ? g_h1z : g_h1f[(t - 1) & 3])
                                      : ((t == 0) ? g_h2z : g_h2f[(t - 1) & 3]);

        // ---- WG-cooperative stage: wave w stages rows ri = r*4+w
        u32x4 stg[NST];
        #pragma unroll
        for (int r = 0; r < NST; ++r) {
            const int ri = r * 4 + w;
            const int ks = ri / NCT, c = ri % NCT;
            if (r < NCXR) {   // compile-time split: x-rows are cached loads
                stg[r] = *(const u32x4*)&srcA[(ks * 4 + ctbase + c) * 64 + lane];
            } else {          // ring rows: coherent bypass loads
                const bf16x8* src = (ks < NKSA)
                    ? &srcA[(ks * 4 + ctbase + c) * 64 + lane]
                    : &srcB[((ks - NKSA) * 4 + ctbase + c) * 64 + lane];
                stg[r] = ldg_cv16(src);
            }
        }
        wait_vm0();
        #pragma unroll
        for (int r = 0; r < NST; ++r)
            ((u32x4*)sB)[(r * 4 + w) * 64 + lane] = stg[r];
        __syncthreads();      // all waves' loads landed + LDS visible

        // ---- consumed posts (plain flag stores; drained by next poll's vmcnt at latest)
        if (L == 0) {
            if (tid == 0) stg_cv_u32(FLG(320 + grp * 32 + ub), Qb + t);
        } else {
            if (tid == 0) stg_cv_u32(FLG(192 + grp * 32 + ub), Qb + t + 1);
            if (tid == 1) stg_cv_u32(FLG(384 + grp * 32 + ub), Qb + t);
        }

        f32x4 acc[NCT];
        #pragma unroll
        for (int c = 0; c < NCT; ++c) acc[c] = biasv;
        #pragma unroll
        for (int ks = 0; ks < NKS; ++ks)
            #pragma unroll
            for (int c = 0; c < NCT; ++c)
                acc[c] = __builtin_amdgcn_mfma_f32_16x16x32_bf16(
                    aF[ks], sB[(ks * NCT + c) * 64 + lane], acc[c], 0, 0, 0);

        // lane (hi,lo): gates i,f,g,o for unit j=jbase+hi, batch b=ct*16+lo
        short* ringW = (short*)((L == 0) ? g_h1f[t & 3] : g_h2f[t & 3]);
        #pragma unroll
        for (int c = 0; c < NCT; ++c) {
            const int ct = ctbase + c;
            const float gi = acc[c][0], gf = acc[c][1];
            const float gg = acc[c][2], go = acc[c][3];
            const float cn_ = sigf(gf) * cst[c] + sigf(gi) * tanh_fast(gg);
            const float hv  = sigf(go) * tanh_fast(cn_);
            cst[c] = cn_;
            stg_cv_u16(&ringW[(((wksp * 4 + ct) * 64) + wkhi * 16 + lo) * 8 + wel],
                       (unsigned)(unsigned short)f2bf(hv));
            if (t == TT - 1) {
                const int j = jbase + hi, b = ct * 16 + lo;
                const size_t base = (size_t)TT * BB * DOUT;
                out[base + (size_t)L * BB * HH + (size_t)b * HH + j] = hv;
                out[base + (size_t)2 * BB * HH + (size_t)L * BB * HH + (size_t)b * HH + j] = cn_;
            }
        }
        wait_vm0();           // ring stores at coherence point
        __syncthreads();      // all waves drained
        if (L == 0) { if (tid == 0) stg_cv_u32(FLG(0 + grp * 32 + ub), Qb + t + 1); }
        else        { if (tid == 0) stg_cv_u32(FLG(64 + grp * 32 + ub), Qb + t + 1); }
    }
}

// ---------------- output projection: 8 WGs = (ob 0..3, cp 0..1); wave = 16 odims
__device__ void run_out(int lwg, int tid,
                        const float* __restrict__ wout, const float* __restrict__ bout,
                        float* __restrict__ out, unsigned Q, bf16x8* sB)
{
    constexpr int NKS  = HH / 32;   // 16 frag-rows
    constexpr int NST  = 8;         // 32 staged rows / 4 waves
    const int lane = tid & 63, lo = lane & 15, hi = lane >> 4;
    const int w = tid >> 6;
    const int cp = lwg & 1, ob = lwg >> 1;
    const int ctbase = cp * 2;
    const int obase = (ob * 4 + w) * 16;
    const unsigned Qb = Q * 2048u;

    bf16x8 aF[NKS];
    #pragma unroll
    for (int ks = 0; ks < NKS; ++ks) {
        const float4* p = (const float4*)(wout + (size_t)(obase + lo) * HH + ks * 32 + hi * 8);
        aF[ks] = pack8(p[0], p[1]);
    }
    f32x4 biasv;
    #pragma unroll
    for (int r = 0; r < 4; ++r) biasv[r] = bout[obase + hi * 4 + r];

    for (int t = 0; t < TT; ++t) {
        const unsigned* wp = g_flg; unsigned wt = 0; int wa = 0;
        if (w == 0) {   // h2[t] ready: quadrants 2cp (lanes 0-31), 2cp+1 (lanes 32-63)
            wp = FLG(64 + (ctbase + (lane >> 5)) * 32 + (lane & 31));
            wt = Qb + t + 1; wa = 1;
        }
        waitpoll(wp, wt, wa, tid);

        const bf16x8* src = g_h2f[t & 3];
        u32x4 stg[NST];
        #pragma unroll
        for (int r = 0; r < NST; ++r) {
            const int ri = r * 4 + w;
            const int ks = ri >> 1, c = ri & 1;
            stg[r] = ldg_cv16(&src[(ks * 4 + ctbase + c) * 64 + lane]);
        }
        wait_vm0();
        #pragma unroll
        for (int r = 0; r < NST; ++r)
            ((u32x4*)sB)[(r * 4 + w) * 64 + lane] = stg[r];
        __syncthreads();
        if (tid == 0) stg_cv_u32(FLG(512 + cp * 4 + ob), Qb + t + 1);

        f32x4 acc[2] = {biasv, biasv};
        #pragma unroll
        for (int ks = 0; ks < NKS; ++ks)
            #pragma unroll
            for (int c = 0; c < 2; ++c)
                acc[c] = __builtin_amdgcn_mfma_f32_16x16x32_bf16(
                    aF[ks], sB[(ks * 2 + c) * 64 + lane], acc[c], 0, 0, 0);
        #pragma unroll
        for (int c = 0; c < 2; ++c)
            #pragma unroll
            for (int r = 0; r < 4; ++r) {
                const int b = (ctbase + c) * 16 + lo, o = obase + hi * 4 + r;
                out[(size_t)t * BB * DOUT + (size_t)b * DOUT + o] = acc[c][r];
            }
    }
}

extern "C" __global__ void __launch_bounds__(256, 1)
lstm2_fused(const float* __restrict__ x,
            const float* __restrict__ wih0, const float* __restrict__ whh0,
            const float* __restrict__ bih0, const float* __restrict__ bhh0,
            const float* __restrict__ wih1, const float* __restrict__ whh1,
            const float* __restrict__ bih1, const float* __restrict__ bhh1,
            const float* __restrict__ wout, const float* __restrict__ bout,
            float* __restrict__ out)
{
    __shared__ bf16x8 sB[3072];   // 48KB: L0 uses all, L1/OUT use 32KB

    const int tid = threadIdx.x, wg = blockIdx.x;
    const unsigned Q = __hip_atomic_load(&g_iter, __ATOMIC_RELAXED, __HIP_MEMORY_SCOPE_AGENT);

    if (wg < NWG_L0)
        run_layer<0, 2>(wg, tid, wih0, whh0, bih0, bhh0, out, Q, sB);
    else if (wg < NWG_L0 + NWG_L1)
        run_layer<1, 1>(wg - NWG_L0, tid, wih1, whh1, bih1, bhh1, out, Q, sB);
    else
        run_out(wg - NWG_L0 - NWG_L1, tid, wout, bout, out, Q, sB);

    // wg0 (an L0 WG) exits only after the pipeline drained; every WG read Q long ago.
    if (wg == 0 && tid == 0)
        __hip_atomic_store(&g_iter, Q + 1, __ATOMIC_RELAXED, __HIP_MEMORY_SCOPE_AGENT);
}

extern "C" void kernel_launch(void* const* d_in, const int* in_sizes, int n_in,
                              void* d_out, int out_size, void* d_ws, size_t ws_size,
                              hipStream_t stream) {
    const float* x    = (const float*)d_in[0];
    const float* wih0 = (const float*)d_in[1];
    const float* whh0 = (const float*)d_in[2];
    const float* bih0 = (const float*)d_in[3];
    const float* bhh0 = (const float*)d_in[4];
    const float* wih1 = (const float*)d_in[5];
    const float* whh1 = (const float*)d_in[6];
    const float* bih1 = (const float*)d_in[7];
    const float* bhh1 = (const float*)d_in[8];
    const float* wout = (const float*)d_in[9];
    const float* bout = (const float*)d_in[10];
    float* out = (float*)d_out;

    hipLaunchKernelGGL(pack_x, dim3(TT), dim3(256), 0, stream, x);
    hipLaunchKernelGGL(lstm2_fused, dim3(NWG_TOT), dim3(256), 0, stream,
                       x, wih0, whh0, bih0, bhh0, wih1, whh1, bih1, bhh1,
                       wout, bout, out);
}

// Round 15
// 3669.006 us; speedup vs baseline: 2.8730x; 1.0515x over previous
//
#include <hip/hip_runtime.h>

#define TT   1024
#define BB   64
#define DIN  256
#define HH   512
#define DOUT 256

#define NWG_L0  64
#define NWG_L1  128
#define NWG_OUT 8
#define NWG_TOT 200

typedef short bf16x8 __attribute__((ext_vector_type(8)));
typedef float f32x4  __attribute__((ext_vector_type(4)));
typedef unsigned u32x4 __attribute__((ext_vector_type(4)));

// frag-ordered bf16 tensors: index f = ((ks*4 + ct)*64 + lane), element e
// value = M[k = ks*32 + (lane>>4)*8 + e][col = ct*16 + (lane&15)]
__device__ bf16x8 g_xf[TT * 2048];     // x packed (static, cached path)
__device__ bf16x8 g_h1f[4][4096];      // h1 ring, 4 slots (coherent-bypass path)
__device__ bf16x8 g_h2f[4][4096];      // h2 ring
__device__ bf16x8 g_h1z[4096];         // t=-1 zeros (never written)
__device__ bf16x8 g_h2z[4096];

// per-producer/per-consumer progress flags, one 64B line each, monotone values
// V = Q*2048 + t + 1 (never reset -> replay-safe). NO atomics. Layout = R14 (proven).
__device__ unsigned g_flg[520 * 16];
__device__ unsigned g_iter;

__device__ __forceinline__ unsigned* FLG(int idx) { return &g_flg[idx * 16]; }

// ---------- explicitly-coherent (IF-level) primitives: bypass L1+L2
__device__ __forceinline__ u32x4 ldg_cv16(const void* p) {
    u32x4 r;
    asm volatile("global_load_dwordx4 %0, %1, off sc0 sc1"
                 : "=&v"(r) : "v"(p) : "memory");
    return r;
}
__device__ __forceinline__ void stg_cv16(void* p, u32x4 v) {
    asm volatile("global_store_dwordx4 %0, %1, off sc0 sc1" :: "v"(p), "v"(v) : "memory");
}
__device__ __forceinline__ void stg_cv_u32(void* p, unsigned v) {
    asm volatile("global_store_dword %0, %1, off sc0 sc1" :: "v"(p), "v"(v) : "memory");
}
__device__ __forceinline__ void wait_vm0(void) {
    asm volatile("s_waitcnt vmcnt(0)" ::: "memory");
}

// ---------- lane-parallel flag wait (UNSIGNED compare; inactive lanes hold ~0)
__device__ __forceinline__ void waitpoll(const unsigned* p, unsigned tgt, int active, int tid) {
    for (;;) {
        unsigned v = 0xFFFFFFFFu;
        if (active)
            asm volatile("global_load_dword %0, %1, off sc0 sc1\n\t"
                         "s_waitcnt vmcnt(0)"
                         : "=&v"(v) : "v"(p) : "memory");
        if (__all(v >= tgt)) break;
        __builtin_amdgcn_s_sleep(1);
    }
    __syncthreads();
}

__device__ __forceinline__ float sigf(float v) { return 1.f / (1.f + __expf(-v)); }
__device__ __forceinline__ float tanh_fast(float v) { return 2.f / (1.f + __expf(-2.f * v)) - 1.f; }

__device__ __forceinline__ short f2bf(float f) {   // RNE float->bf16 bits
    unsigned u = __builtin_bit_cast(unsigned, f);
    unsigned r = (u + 0x7FFFu + ((u >> 16) & 1u)) >> 16;
    return (short)r;
}

__device__ __forceinline__ bf16x8 pack8(float4 v0, float4 v1) {
    bf16x8 r;
    r[0] = f2bf(v0.x); r[1] = f2bf(v0.y); r[2] = f2bf(v0.z); r[3] = f2bf(v0.w);
    r[4] = f2bf(v1.x); r[5] = f2bf(v1.y); r[6] = f2bf(v1.z); r[7] = f2bf(v1.w);
    return r;
}

// ---------------- pre-pass: pack x (fp32 [T][B][DIN]) into frag-ordered bf16
extern "C" __global__ void __launch_bounds__(256)
pack_x(const float* __restrict__ x) {
    const int t = blockIdx.x, tid = threadIdx.x;
    const float* xt = x + (size_t)t * BB * DIN;
    bf16x8* dst = g_xf + (size_t)t * 2048;
    #pragma unroll
    for (int u = 0; u < 8; ++u) {
        const int f = u * 256 + tid;
        const int lane_ = f & 63, ctks = f >> 6;
        const int ct = ctks & 3, ks = ctks >> 2;
        const int b  = ct * 16 + (lane_ & 15);
        const int kb = ks * 32 + (lane_ >> 4) * 8;
        const float4* s = (const float4*)(xt + b * DIN + kb);
        dst[f] = pack8(s[0], s[1]);
    }
}

// ---------------- LSTM layer, split-phase. WG = (ub, NCT quadrants); wave = 4 units.
// L=0: A-rows = x (cached, no wait), B-rows = h1[t-1]. L=1: A = h1[t], B = h2[t-1].
template<int L, int NCT>
__device__ void run_layer(int lwg, int tid,
                          const float* __restrict__ wih, const float* __restrict__ whh,
                          const float* __restrict__ bih, const float* __restrict__ bhh,
                          float* __restrict__ out, unsigned Q, bf16x8* sB, short* sH)
{
    constexpr int KINX = (L == 0) ? DIN : HH;
    constexpr int NKSA = KINX / 32;          // A frag-rows per ct (8 or 16)
    constexpr int NKS  = NKSA + HH / 32;     // total (24 or 32)
    constexpr int NSTA = NKSA * NCT / 4;     // A rows staged per wave (4)
    constexpr int NSTB = (HH / 32) * NCT / 4;// B rows staged per wave (8 or 4)

    const int lane = tid & 63, lo = lane & 15, hi = lane >> 4;
    const int w      = tid >> 6;
    const int ctbase = (NCT == 2) ? (lwg & 1) * 2 : (lwg & 3);
    const int grp    = (NCT == 2) ? (lwg & 1) : (lwg & 3);        // p or ct
    const int ub     = (NCT == 2) ? (lwg >> 1) : (lwg >> 2);      // 0..31
    const int wv     = ub * 4 + w;
    const int jbase  = wv * 4;
    const int grow   = (lo & 3) * HH + jbase + (lo >> 2);  // gate-major A-row for lane lo

    // --- weights as bf16 A-fragments in registers (loaded once, cached)
    bf16x8 aF[NKS];
    #pragma unroll
    for (int ks = 0; ks < NKS; ++ks) {
        const float* wr;
        if (ks < NKSA) wr = wih + (size_t)grow * KINX + ks * 32 + hi * 8;
        else           wr = whh + (size_t)grow * HH + (ks - NKSA) * 32 + hi * 8;
        const float4* p = (const float4*)wr;
        aF[ks] = pack8(p[0], p[1]);
    }

    f32x4 biasv;
    #pragma unroll
    for (int r = 0; r < 4; ++r)
        biasv[r] = bih[r * HH + jbase + hi] + bhh[r * HH + jbase + hi];

    const unsigned Qb = Q * 2048u;
    float cst[NCT];
    #pragma unroll
    for (int c = 0; c < NCT; ++c) cst[c] = 0.f;

    for (int t = 0; t < TT; ++t) {
        const bf16x8* srcA = (L == 0) ? (g_xf + (size_t)t * 2048) : g_h1f[t & 3];
        const bf16x8* srcB = (L == 0) ? ((t == 0) ? g_h1z : g_h1f[(t - 1) & 3])
                                      : ((t == 0) ? g_h2z : g_h2f[(t - 1) & 3]);

        // ---- Phase A gate (L1 only): h1[t] ready
        if (L == 1) {
            const unsigned* wp = g_flg; unsigned wt = 0; int wa = 0;
            if (w == 0 && lane < 32) { wp = FLG(0 + (grp >> 1) * 32 + lane);
                                       wt = Qb + t + 1; wa = 1; }
            waitpoll(wp, wt, wa, tid);
        }

        // ---- Phase A stage: rows [0 .. NKSA*NCT)
        u32x4 stgA[NSTA];
        #pragma unroll
        for (int r = 0; r < NSTA; ++r) {
            const int ri = r * 4 + w, ks = ri / NCT, c = ri % NCT;
            const bf16x8* src = &srcA[(ks * 4 + ctbase + c) * 64 + lane];
            if (L == 0) stgA[r] = *(const u32x4*)src;   // cached x
            else        stgA[r] = ldg_cv16(src);        // bypass h1
        }
        wait_vm0();
        #pragma unroll
        for (int r = 0; r < NSTA; ++r)
            ((u32x4*)sB)[(r * 4 + w) * 64 + lane] = stgA[r];

        // ---- recurrent gate: B operand ready (trailing sync also publishes A in LDS)
        {
            const unsigned* wp = g_flg; unsigned wt = 0; int wa = 0;
            if (w == 0 && lane < 32 && t >= 1) {
                wp = (L == 0) ? FLG(0 + grp * 32 + lane) : FLG(64 + grp * 32 + lane);
                wt = Qb + t; wa = 1;
            }
            waitpoll(wp, wt, wa, tid);
        }
        // consumed-post for A (L1: h1[t] now safe in LDS)
        if (L == 1 && tid == 0) stg_cv_u32(FLG(192 + grp * 32 + ub), Qb + t + 1);

        // ---- Phase B: issue recurrent loads, overlap partial MFMA over A rows
        u32x4 stgB[NSTB];
        #pragma unroll
        for (int r = 0; r < NSTB; ++r) {
            const int ri = r * 4 + w, ks = ri / NCT, c = ri % NCT;
            stgB[r] = ldg_cv16(&srcB[(ks * 4 + ctbase + c) * 64 + lane]);
        }
        f32x4 acc[NCT];
        #pragma unroll
        for (int c = 0; c < NCT; ++c) acc[c] = biasv;
        #pragma unroll
        for (int ks = 0; ks < NKSA; ++ks)
            #pragma unroll
            for (int c = 0; c < NCT; ++c)
                acc[c] = __builtin_amdgcn_mfma_f32_16x16x32_bf16(
                    aF[ks], sB[(ks * NCT + c) * 64 + lane], acc[c], 0, 0, 0);
        wait_vm0();
        #pragma unroll
        for (int r = 0; r < NSTB; ++r)
            ((u32x4*)sB)[(NKSA * NCT + r * 4 + w) * 64 + lane] = stgB[r];
        __syncthreads();
        // consumed-post for B
        if (tid == 0) {
            if (L == 0) stg_cv_u32(FLG(320 + grp * 32 + ub), Qb + t);
            else        stg_cv_u32(FLG(384 + grp * 32 + ub), Qb + t);
        }
        #pragma unroll
        for (int ks = NKSA; ks < NKS; ++ks)
            #pragma unroll
            for (int c = 0; c < NCT; ++c)
                acc[c] = __builtin_amdgcn_mfma_f32_16x16x32_bf16(
                    aF[ks], sB[(ks * NCT + c) * 64 + lane], acc[c], 0, 0, 0);

        // ---- activation; pack h into sH (frag-ordered: e=(w&1)*4+hi, hi2=w>>1)
        #pragma unroll
        for (int c = 0; c < NCT; ++c) {
            const float gi = acc[c][0], gf = acc[c][1];
            const float gg = acc[c][2], go = acc[c][3];
            const float cn_ = sigf(gf) * cst[c] + sigf(gi) * tanh_fast(gg);
            const float hv  = sigf(go) * tanh_fast(cn_);
            cst[c] = cn_;
            sH[((c * 2 + (w >> 1)) * 16 + lo) * 8 + (w & 1) * 4 + hi] = f2bf(hv);
            if (t == TT - 1) {
                const int j = jbase + hi, b = (ctbase + c) * 16 + lo;
                const size_t base = (size_t)TT * BB * DOUT;
                out[base + (size_t)L * BB * HH + (size_t)b * HH + j] = hv;
                out[base + (size_t)2 * BB * HH + (size_t)L * BB * HH + (size_t)b * HH + j] = cn_;
            }
        }

        // ---- deferred back-pressure: slot (t&3) free? (R14 flags/targets, proven)
        {
            const unsigned* wp = g_flg; unsigned wt = 0; int wa = 0;
            if (t >= 4) {
                if (L == 0) {
                    if (w == 1) { wp = FLG(192 + (grp * 2 + (lane >> 5)) * 32 + (lane & 31));
                                  wt = Qb + t - 3; wa = 1; }
                    else if (w == 2 && lane < 32) { wp = FLG(320 + grp * 32 + lane);
                                                    wt = Qb + t - 3; wa = 1; }
                } else {
                    if (w == 1) {
                        if (lane < 32)      { wp = FLG(384 + grp * 32 + lane);
                                              wt = Qb + t - 3; wa = 1; }
                        else if (lane < 36) { wp = FLG(512 + (grp >> 1) * 4 + (lane - 32));
                                              wt = Qb + t - 3; wa = 1; }
                    }
                }
            }
            waitpoll(wp, wt, wa, tid);   // trailing sync also publishes sH
        }

        // ---- wave0: wide 16B ring stores from sH, then post ready
        u32x4* ringW = (u32x4*)((L == 0) ? g_h1f[t & 3] : g_h2f[t & 3]);
        if (tid < 32 * NCT) {
            const int c = tid >> 5, r = tid & 31, hi2 = r >> 4, lo2 = r & 15;
            const int f = ((ub >> 1) * 4 + ctbase + c) * 64 + ((ub & 1) * 2 + hi2) * 16 + lo2;
            stg_cv16(ringW + f, *(const u32x4*)&sH[((c * 2 + hi2) * 16 + lo2) * 8]);
        }
        wait_vm0();   // wave0's stores at coherence point (other waves: no-op)
        if (tid == 0) {
            if (L == 0) stg_cv_u32(FLG(0 + grp * 32 + ub), Qb + t + 1);
            else        stg_cv_u32(FLG(64 + grp * 32 + ub), Qb + t + 1);
        }
        // no trailing barrier needed: only wave0 touched sH/ring; next-step syncs cover reuse
    }
}

// ---------------- output projection: 8 WGs = (ob 0..3, cp 0..1); wave = 16 odims
__device__ void run_out(int lwg, int tid,
                        const float* __restrict__ wout, const float* __restrict__ bout,
                        float* __restrict__ out, unsigned Q, bf16x8* sB)
{
    constexpr int NKS  = HH / 32;   // 16 frag-rows
    constexpr int NST  = 8;         // 32 staged rows / 4 waves
    const int lane = tid & 63, lo = lane & 15, hi = lane >> 4;
    const int w = tid >> 6;
    const int cp = lwg & 1, ob = lwg >> 1;
    const int ctbase = cp * 2;
    const int obase = (ob * 4 + w) * 16;
    const unsigned Qb = Q * 2048u;

    bf16x8 aF[NKS];
    #pragma unroll
    for (int ks = 0; ks < NKS; ++ks) {
        const float4* p = (const float4*)(wout + (size_t)(obase + lo) * HH + ks * 32 + hi * 8);
        aF[ks] = pack8(p[0], p[1]);
    }
    f32x4 biasv;
    #pragma unroll
    for (int r = 0; r < 4; ++r) biasv[r] = bout[obase + hi * 4 + r];

    for (int t = 0; t < TT; ++t) {
        const unsigned* wp = g_flg; unsigned wt = 0; int wa = 0;
        if (w == 0) {   // h2[t] ready: quadrants 2cp (lanes 0-31), 2cp+1 (lanes 32-63)
            wp = FLG(64 + (ctbase + (lane >> 5)) * 32 + (lane & 31));
            wt = Qb + t + 1; wa = 1;
        }
        waitpoll(wp, wt, wa, tid);

        const bf16x8* src = g_h2f[t & 3];
        u32x4 stg[NST];
        #pragma unroll
        for (int r = 0; r < NST; ++r) {
            const int ri = r * 4 + w;
            const int ks = ri >> 1, c = ri & 1;
            stg[r] = ldg_cv16(&src[(ks * 4 + ctbase + c) * 64 + lane]);
        }
        wait_vm0();
        #pragma unroll
        for (int r = 0; r < NST; ++r)
            ((u32x4*)sB)[(r * 4 + w) * 64 + lane] = stg[r];
        __syncthreads();
        if (tid == 0) stg_cv_u32(FLG(512 + cp * 4 + ob), Qb + t + 1);

        f32x4 acc[2] = {biasv, biasv};
        #pragma unroll
        for (int ks = 0; ks < NKS; ++ks)
            #pragma unroll
            for (int c = 0; c < 2; ++c)
                acc[c] = __builtin_amdgcn_mfma_f32_16x16x32_bf16(
                    aF[ks], sB[(ks * 2 + c) * 64 + lane], acc[c], 0, 0, 0);
        #pragma unroll
        for (int c = 0; c < 2; ++c)
            #pragma unroll
            for (int r = 0; r < 4; ++r) {
                const int b = (ctbase + c) * 16 + lo, o = obase + hi * 4 + r;
                out[(size_t)t * BB * DOUT + (size_t)b * DOUT + o] = acc[c][r];
            }
    }
}

extern "C" __global__ void __launch_bounds__(256, 1)
lstm2_fused(const float* __restrict__ x,
            const float* __restrict__ wih0, const float* __restrict__ whh0,
            const float* __restrict__ bih0, const float* __restrict__ bhh0,
            const float* __restrict__ wih1, const float* __restrict__ whh1,
            const float* __restrict__ bih1, const float* __restrict__ bhh1,
            const float* __restrict__ wout, const float* __restrict__ bout,
            float* __restrict__ out)
{
    __shared__ bf16x8 sB[3072];                      // 48KB staging
    __shared__ __align__(16) short sH[2 * 2 * 16 * 8];  // 1KB h-pack buffer

    const int tid = threadIdx.x, wg = blockIdx.x;
    const unsigned Q = __hip_atomic_load(&g_iter, __ATOMIC_RELAXED, __HIP_MEMORY_SCOPE_AGENT);

    if (wg < NWG_L0)
        run_layer<0, 2>(wg, tid, wih0, whh0, bih0, bhh0, out, Q, sB, sH);
    else if (wg < NWG_L0 + NWG_L1)
        run_layer<1, 1>(wg - NWG_L0, tid, wih1, whh1, bih1, bhh1, out, Q, sB, sH);
    else
        run_out(wg - NWG_L0 - NWG_L1, tid, wout, bout, out, Q, sB);

    if (wg == 0 && tid == 0)
        __hip_atomic_store(&g_iter, Q + 1, __ATOMIC_RELAXED, __HIP_MEMORY_SCOPE_AGENT);
}

extern "C" void kernel_launch(void* const* d_in, const int* in_sizes, int n_in,
                              void* d_out, int out_size, void* d_ws, size_t ws_size,
                              hipStream_t stream) {
    const float* x    = (const float*)d_in[0];
    const float* wih0 = (const float*)d_in[1];
    const float* whh0 = (const float*)d_in[2];
    const float* bih0 = (const float*)d_in[3];
    const float* bhh0 = (const float*)d_in[4];
    const float* wih1 = (const float*)d_in[5];
    const float* whh1 = (const float*)d_in[6];
    const float* bih1 = (const float*)d_in[7];
    const float* bhh1 = (const float*)d_in[8];
    const float* wout = (const float*)d_in[9];
    const float* bout = (const float*)d_in[10];
    float* out = (float*)d_out;

    hipLaunchKernelGGL(pack_x, dim3(TT), dim3(256), 0, stream, x);
    hipLaunchKernelGGL(lstm2_fused, dim3(NWG_TOT), dim3(256), 0, stream,
                       x, wih0, whh0, bih0, bhh0, wih1, whh1, bih1, bhh1,
                       wout, bout, out);
}